// Round 4
// baseline (540.012 us; speedup 1.0000x reference)
//
#include <hip/hip_runtime.h>
#include <hip/hip_bf16.h>

// Problem constants
#define B_  2
#define S_  2048
#define HID_ 2048
#define H_  16
#define HKV_ 4
#define D_  128

typedef __bf16 bf16_t;
typedef bf16_t bf16x8 __attribute__((ext_vector_type(8)));
typedef float f32x4 __attribute__((ext_vector_type(4)));

typedef __attribute__((address_space(3))) unsigned int lds_u32_t;
typedef const __attribute__((address_space(1))) unsigned int glob_u32_t;

// async global->LDS, 16 B per lane; LDS dest = wave-uniform base + lane*16
__device__ __forceinline__ void gl2lds16(const bf16_t* g, bf16_t* l) {
    __builtin_amdgcn_global_load_lds((glob_u32_t*)g, (lds_u32_t*)l, 16, 0, 0);
}

__device__ __forceinline__ unsigned packbf2(float a, float b) {
    union { bf16_t h[2]; unsigned u; } p;
    p.h[0] = (bf16_t)a;
    p.h[1] = (bf16_t)b;
    return p.u;
}

// ---------------------------------------------------------------------------
// Runtime dtype detection: flag=1 if inputs are bf16, 0 if fp32.
// ---------------------------------------------------------------------------
__global__ void detect_dtype(const unsigned* __restrict__ x, int* __restrict__ flag) {
    int lane = threadIdx.x;
    int c = 0;
#pragma unroll
    for (int i = 0; i < 16; ++i) {
        unsigned w = x[lane * 16 + i];
        unsigned e = (w >> 7) & 0xFF;
        c += (e >= 117 && e <= 137) ? 1 : 0;
    }
#pragma unroll
    for (int m = 1; m < 64; m <<= 1) c += __shfl_xor(c, m, 64);
    if (lane == 0) *flag = (c >= 512) ? 1 : 0;
}

// ---------------------------------------------------------------------------
// Conversion pass: src (fp32 or bf16 per flag) -> bf16 dst. 8 elems/thread.
// ---------------------------------------------------------------------------
struct Cseg { const void* src; bf16_t* dst; int n8; };

__global__ __launch_bounds__(256) void convert_bf16(Cseg s0, Cseg s1, Cseg s2, Cseg s3,
                                                    const int* __restrict__ flagp) {
    Cseg s = (blockIdx.y == 0) ? s0 : (blockIdx.y == 1) ? s1 : (blockIdx.y == 2) ? s2 : s3;
    const int i = blockIdx.x * 256 + threadIdx.x;
    if (i >= s.n8) return;
    if (*flagp) {
        ((uint4*)s.dst)[i] = ((const uint4*)s.src)[i];
    } else {
        const float4* p = (const float4*)s.src + (size_t)i * 2;
        float4 u = p[0], v = p[1];
        bf16x8 r;
        r[0] = (bf16_t)u.x; r[1] = (bf16_t)u.y; r[2] = (bf16_t)u.z; r[3] = (bf16_t)u.w;
        r[4] = (bf16_t)v.x; r[5] = (bf16_t)v.y; r[6] = (bf16_t)v.z; r[7] = (bf16_t)v.w;
        *(bf16x8*)(s.dst + (size_t)i * 8) = r;
    }
}

// ---------------------------------------------------------------------------
// m97-structure GEMM: C[m,n] = sum_k A[m,k]*W[n,k], A/W bf16 row-major.
// 128x128 tile, BK=32, LDS staging via global_load_lds width=16.
// ---------------------------------------------------------------------------
__global__ __launch_bounds__(256) void gemm_lds(const bf16_t* __restrict__ A,
                                                const bf16_t* __restrict__ W,
                                                void* __restrict__ C,
                                                int M, int N, int K,
                                                const int* __restrict__ flagp, int osel) {
    __shared__ bf16_t As[128 * 32];
    __shared__ bf16_t Bs[128 * 32];

    const int tid = threadIdx.x;
    const int w = tid >> 6;
    const int lane = tid & 63;
    const int r = lane & 15;
    const int quad = lane >> 4;
    const int m0 = blockIdx.y * 128;
    const int n0 = blockIdx.x * 128;
    const bool of32 = osel && (*flagp == 0);

    const int mh = (w & 1) * 64;
    const int nh = (w >> 1) * 64;

    const int c0 = w * 2;
    const int srow = lane >> 2;
    const int scol = (lane & 3) * 8;
    const bf16_t* Ag0 = A + (size_t)(m0 + c0 * 16 + srow) * K + scol;
    const bf16_t* Ag1 = A + (size_t)(m0 + c0 * 16 + 16 + srow) * K + scol;
    const bf16_t* Wg0 = W + (size_t)(n0 + c0 * 16 + srow) * K + scol;
    const bf16_t* Wg1 = W + (size_t)(n0 + c0 * 16 + 16 + srow) * K + scol;
    bf16_t* Al0 = As + c0 * 512;
    bf16_t* Al1 = As + (c0 + 1) * 512;
    bf16_t* Bl0 = Bs + c0 * 512;
    bf16_t* Bl1 = Bs + (c0 + 1) * 512;

    f32x4 acc[4][4] = {};

    for (int k0 = 0; k0 < K; k0 += 32) {
        __syncthreads();
        gl2lds16(Ag0 + k0, Al0);
        gl2lds16(Ag1 + k0, Al1);
        gl2lds16(Wg0 + k0, Bl0);
        gl2lds16(Wg1 + k0, Bl1);
        __syncthreads();

        bf16x8 a[4], b[4];
#pragma unroll
        for (int mi = 0; mi < 4; ++mi)
            a[mi] = *(const bf16x8*)&As[(mh + mi * 16 + r) * 32 + quad * 8];
#pragma unroll
        for (int ni = 0; ni < 4; ++ni)
            b[ni] = *(const bf16x8*)&Bs[(nh + ni * 16 + r) * 32 + quad * 8];
#pragma unroll
        for (int mi = 0; mi < 4; ++mi)
#pragma unroll
            for (int ni = 0; ni < 4; ++ni)
                acc[mi][ni] = __builtin_amdgcn_mfma_f32_16x16x32_bf16(a[mi], b[ni], acc[mi][ni], 0, 0, 0);
    }

#pragma unroll
    for (int mi = 0; mi < 4; ++mi) {
#pragma unroll
        for (int ni = 0; ni < 4; ++ni) {
#pragma unroll
            for (int g = 0; g < 4; ++g) {
                const int row = m0 + mh + mi * 16 + quad * 4 + g;
                const int col = n0 + nh + ni * 16 + r;
                if (of32) ((float*)C)[(size_t)row * N + col] = acc[mi][ni][g];
                else ((__hip_bfloat16*)C)[(size_t)row * N + col] = __float2bfloat16(acc[mi][ni][g]);
            }
        }
    }
}

// ---------------------------------------------------------------------------
// Fallback direct-from-global GEMM (proven path).
// ---------------------------------------------------------------------------
template <bool F32>
__device__ __forceinline__ bf16x8 load8(const void* base, size_t off) {
    bf16x8 r;
    if constexpr (F32) {
        const float4* p = (const float4*)((const float*)base + off);
        float4 u = p[0], v = p[1];
        r[0] = (bf16_t)u.x; r[1] = (bf16_t)u.y; r[2] = (bf16_t)u.z; r[3] = (bf16_t)u.w;
        r[4] = (bf16_t)v.x; r[5] = (bf16_t)v.y; r[6] = (bf16_t)v.z; r[7] = (bf16_t)v.w;
    } else {
        r = *(const bf16x8*)((const bf16_t*)base + off);
    }
    return r;
}

template <bool AF32, bool WF32, bool OF32>
__device__ __forceinline__ void gemm_body(const void* __restrict__ A, const void* __restrict__ W,
                                          void* __restrict__ C, int M, int N, int K) {
    const int wave = threadIdx.x >> 6;
    const int lane = threadIdx.x & 63;
    const int r = lane & 15;
    const int quad = lane >> 4;
    const int m0 = blockIdx.y * 64 + wave * 16;
    const int n0 = blockIdx.x * 64;

    f32x4 acc[4] = {};
    const size_t aoff = (size_t)(m0 + r) * K + quad * 8;
    const size_t woff = (size_t)(n0 + r) * K + quad * 8;

    for (int k0 = 0; k0 < K; k0 += 32) {
        bf16x8 a = load8<AF32>(A, aoff + k0);
#pragma unroll
        for (int ns = 0; ns < 4; ++ns) {
            bf16x8 b = load8<WF32>(W, woff + (size_t)(ns * 16) * K + k0);
            acc[ns] = __builtin_amdgcn_mfma_f32_16x16x32_bf16(a, b, acc[ns], 0, 0, 0);
        }
    }

#pragma unroll
    for (int ns = 0; ns < 4; ++ns) {
#pragma unroll
        for (int reg = 0; reg < 4; ++reg) {
            int m = m0 + quad * 4 + reg;
            int n = n0 + ns * 16 + r;
            if constexpr (OF32) ((float*)C)[(size_t)m * N + n] = acc[ns][reg];
            else ((__hip_bfloat16*)C)[(size_t)m * N + n] = __float2bfloat16(acc[ns][reg]);
        }
    }
}

__global__ __launch_bounds__(256) void gemm_bt(const void* __restrict__ A, const void* __restrict__ W,
                                               void* __restrict__ C, int M, int N, int K,
                                               const int* __restrict__ flagp, int mode) {
    const int bf = *flagp;
    if (bf) {
        gemm_body<false, false, false>(A, W, C, M, N, K);
    } else if (mode == 0) {
        gemm_body<true, true, false>(A, W, C, M, N, K);
    } else {
        gemm_body<false, true, true>(A, W, C, M, N, K);
    }
}

// ---------------------------------------------------------------------------
// In-place RoPE + RMSNorm on bf16 rows. Row (bs,h) at base + bs*ld + h*D.
// ---------------------------------------------------------------------------
__global__ __launch_bounds__(256) void rope_rms(__hip_bfloat16* __restrict__ qk,
                                                const void* __restrict__ cosp,
                                                const void* __restrict__ sinp,
                                                int NH, int ld, const int* __restrict__ flagp) {
    const int bf = *flagp;
    const int wave = threadIdx.x >> 6;
    const int lane = threadIdx.x & 63;
    const int row = blockIdx.x * 4 + wave;   // row = bs*NH + h
    const int h = row % NH;
    const int bs = row / NH;
    const int s = bs % S_;

    __hip_bfloat16* p = qk + (size_t)bs * ld + h * D_;
    float x1 = __bfloat162float(p[lane]);
    float x2 = __bfloat162float(p[lane + 64]);
    float c, sn, eps;
    if (bf) {
        c   = __bfloat162float(((const __hip_bfloat16*)cosp)[s * 64 + lane]);
        sn  = __bfloat162float(((const __hip_bfloat16*)sinp)[s * 64 + lane]);
        eps = 0.0078125f;
    } else {
        c   = ((const float*)cosp)[s * 64 + lane];
        sn  = ((const float*)sinp)[s * 64 + lane];
        eps = 1.1920929e-07f;
    }
    float y1 = x1 * c + x2 * sn;
    float y2 = x2 * c - x1 * sn;
    float ss = y1 * y1 + y2 * y2;
#pragma unroll
    for (int m = 1; m < 64; m <<= 1) ss += __shfl_xor(ss, m, 64);
    float rinv = rsqrtf(ss * (1.0f / 128.0f) + eps);
    p[lane]      = __float2bfloat16(y1 * rinv);
    p[lane + 64] = __float2bfloat16(y2 * rinv);
}

// ---------------------------------------------------------------------------
// K pack: post-RoPE K (strided in qkv) -> Kp[gy][kt][row32][d] bf16.
// Per (group, key-tile) the 32x128 tile is one contiguous 8 KB chunk.
// ---------------------------------------------------------------------------
__global__ __launch_bounds__(256) void k_pack(const __hip_bfloat16* __restrict__ Kin,
                                              bf16_t* __restrict__ Kp) {
    const int idx = blockIdx.x * 256 + threadIdx.x;   // 8 bf16 per thread
    const int d0 = (idx & 15) * 8;
    const int row = (idx >> 4) & 31;
    const int kt = (idx >> 9) & 63;
    const int gy = idx >> 15;
    const int kvh = gy & 3;
    const int bb = gy >> 2;
    const bf16_t* src = (const bf16_t*)Kin + (size_t)(bb * S_ + kt * 32 + row) * 3072 + kvh * D_ + d0;
    *(uint4*)(Kp + (size_t)idx * 8) = *(const uint4*)src;
}

// ---------------------------------------------------------------------------
// V pair-pack transpose: V[s][d] (strided in qkv) -> Vp[gy][kt][d][kp] u32
// where u32 = (V[32kt+kp][d], V[32kt+16+kp][d]).  kp = quad*4 + word is the
// fragment pair order the Pb path produces.
// ---------------------------------------------------------------------------
__global__ __launch_bounds__(256) void v_pack(const __hip_bfloat16* __restrict__ V,
                                              unsigned* __restrict__ Vp, int ldv) {
    const int idx = blockIdx.x * 256 + threadIdx.x;
    const int kp = idx & 15;
    const int d  = (idx >> 4) & 127;
    const int kt = (idx >> 11) & 63;
    const int gy = idx >> 17;                 // b*HKV + kvh
    const int kvh = gy & 3;
    const int b = gy >> 2;
    const unsigned short* p = (const unsigned short*)V
        + (size_t)(b * S_ + 32 * kt + kp) * ldv + kvh * D_ + d;
    unsigned lo = p[0];
    unsigned hi = p[(size_t)16 * ldv];
    Vp[idx] = lo | (hi << 16);
}

// ---------------------------------------------------------------------------
// Flash attention v6: fully independent waves + register-prefetch pipeline.
//
// Cross-round invariant v3/v4/v5: ~6000 cyc per key-tile iteration per SIMD
// regardless of structure -> stalls are CORRELATED (barriers resync waves;
// no prefetch exposes 2x L2 latency per iter serially). Fix both:
//  - ZERO barriers: each wave owns one full (head, q-tile); no key split, no
//    merge. Wave w and w^4 (same SIMD under round-robin w&3) get
//    complementary tiles T and 63-T -> every SIMD does exactly 65 iters.
//  - Register A/B double-buffer: tile kt+1's 16 loads (8 K + 8 V, 16 B each)
//    issue before computing tile kt; compiler emits counted vmcnt waits.
//  - Coalesced O epilogue: per-wave LDS transpose (bf16 [32][136]) then
//    16 B/lane dwordx4 stores = full 128 B lines (kills the partial-line RMW
//    that produced 74 MB WRITE_SIZE in v5).
// Keeps (hardware-verified in v5): fixed-max softmax, Pb pair-pack algebra,
// packed K/V layouts, s_setprio around MFMA clusters, XCD pin gy = id&7.
// Grid 256 x 512 thr: 1 block/CU, 8 waves/CU.  LDS 84 KB.
// ---------------------------------------------------------------------------
#define M0F 16.5f

__global__ __launch_bounds__(512, 2) void attn_flash6(const __hip_bfloat16* __restrict__ Q,
                                                      const bf16_t* __restrict__ Kp,
                                                      const unsigned* __restrict__ Vp,
                                                      __hip_bfloat16* __restrict__ O) {
    __shared__ unsigned PbS[8][2][16][16];   // 16 KB, wave-private P pair-pack
    __shared__ bf16_t  Os[8][32][136];       // 68 KB, wave-private O transpose

    const int tid = threadIdx.x;
    const int w = tid >> 6;
    const int lane = tid & 63;
    const int r = lane & 15;
    const int quad = lane >> 4;

    const int id = blockIdx.x;
    const int gy = id & 7;                  // group -> XCD pin
    const int u = id >> 3;
    const int hh = u & 3;
    const int i = u >> 2;                   // 0..7
    const int kvh = gy & 3;
    const int b = gy >> 2;
    const int h = kvh * 4 + hh;

    // Complementary tile table: lower-half waves w=0..3 get
    // {i, 31-i, 16+i, 15-i}; waves w+4 get 63 - that.  Covers 0..63 exactly
    // across i=0..7; SIMD (w&3) hosts w and w^4 -> per-SIMD work = 65 tiles.
    const int s4 = w & 3;
    int tlo = (s4 == 0) ? i : (s4 == 1) ? (31 - i) : (s4 == 2) ? (16 + i) : (15 - i);
    const int qt = (w < 4) ? tlo : (63 - tlo);
    const int q0 = qt * 32;

    const bf16_t* Kg = Kp + (size_t)gy * (64 * 32 * 128);
    const unsigned* Vg = Vp + (size_t)gy * (64 * 128 * 16);

    // Q fragments
    bf16x8 qf[2][4];
#pragma unroll
    for (int t = 0; t < 2; ++t) {
        const bf16_t* qp = (const bf16_t*)Q + (size_t)(b * S_ + q0 + t * 16 + r) * 3072 + h * D_ + quad * 8;
#pragma unroll
        for (int c = 0; c < 4; ++c) qf[t][c] = *(const bf16x8*)(qp + c * 32);
    }

    f32x4 oacc[2][8] = {};
    f32x4 lacc[2] = {};

    bf16x8 ones;
#pragma unroll
    for (int j = 0; j < 8; ++j) ones[j] = (bf16_t)1.0f;

    const float SC2 = 0.08838834764831845f * 1.4426950408889634f;  // D^-0.5 * log2(e)

    unsigned* pbw = &PbS[w][0][0][0];
    const int pwi = (((r >> 2) ^ quad) & 3) * 4 + (r & 3);   // write slot
    const int pgrp = ((quad ^ (r >> 2)) & 3) * 4;            // read group

    bf16x8 ka[8], va[8], kb[8], vb[8];

#define LOADKV(KB, VB, KT) do {                                               \
        const bf16_t* kp_ = Kg + (size_t)(KT) * 4096 + r * 128 + quad * 8;    \
        const unsigned* vp_ = Vg + (size_t)(KT) * 2048 + r * 16 + quad * 4;   \
        KB[0] = *(const bf16x8*)(kp_);                                        \
        KB[1] = *(const bf16x8*)(kp_ + 2048);                                 \
        KB[2] = *(const bf16x8*)(kp_ + 32);                                   \
        KB[3] = *(const bf16x8*)(kp_ + 2048 + 32);                            \
        KB[4] = *(const bf16x8*)(kp_ + 64);                                   \
        KB[5] = *(const bf16x8*)(kp_ + 2048 + 64);                            \
        KB[6] = *(const bf16x8*)(kp_ + 96);                                   \
        KB[7] = *(const bf16x8*)(kp_ + 2048 + 96);                            \
        VB[0] = *(const bf16x8*)(vp_);                                        \
        VB[1] = *(const bf16x8*)(vp_ + 256);                                  \
        VB[2] = *(const bf16x8*)(vp_ + 512);                                  \
        VB[3] = *(const bf16x8*)(vp_ + 768);                                  \
        VB[4] = *(const bf16x8*)(vp_ + 1024);                                 \
        VB[5] = *(const bf16x8*)(vp_ + 1280);                                 \
        VB[6] = *(const bf16x8*)(vp_ + 1536);                                 \
        VB[7] = *(const bf16x8*)(vp_ + 1792);                                 \
    } while (0)

#define COMPUTE(KB, VB, KT) do {                                              \
        f32x4 s0_[2] = {}, s1_[2] = {};                                       \
        __builtin_amdgcn_s_setprio(1);                                        \
        _Pragma("unroll")                                                     \
        for (int c = 0; c < 4; ++c) {                                         \
            _Pragma("unroll")                                                 \
            for (int t = 0; t < 2; ++t) {                                     \
                s0_[t] = __builtin_amdgcn_mfma_f32_16x16x32_bf16(qf[t][c], KB[c * 2], s0_[t], 0, 0, 0);     \
                s1_[t] = __builtin_amdgcn_mfma_f32_16x16x32_bf16(qf[t][c], KB[c * 2 + 1], s1_[t], 0, 0, 0); \
            }                                                                 \
        }                                                                     \
        __builtin_amdgcn_s_setprio(0);                                        \
        if ((KT) == qt) {                                                     \
            _Pragma("unroll")                                                 \
            for (int t = 0; t < 2; ++t)                                       \
                _Pragma("unroll")                                             \
                for (int g = 0; g < 4; ++g) {                                 \
                    const int qrow_ = q0 + t * 16 + quad * 4 + g;             \
                    if ((KT) * 32 + r > qrow_)      s0_[t][g] = -1e38f;       \
                    if ((KT) * 32 + 16 + r > qrow_) s1_[t][g] = -1e38f;       \
                }                                                             \
        }                                                                     \
        _Pragma("unroll")                                                     \
        for (int t = 0; t < 2; ++t)                                           \
            _Pragma("unroll")                                                 \
            for (int g = 0; g < 4; ++g) {                                     \
                const float p0_ = exp2f(fmaf(s0_[t][g], SC2, -M0F));          \
                const float p1_ = exp2f(fmaf(s1_[t][g], SC2, -M0F));          \
                pbw[t * 256 + (quad * 4 + g) * 16 + pwi] = packbf2(p0_, p1_); \
            }                                                                 \
        bf16x8 pf0_ = *(const bf16x8*)&pbw[r * 16 + pgrp];                    \
        bf16x8 pf1_ = *(const bf16x8*)&pbw[256 + r * 16 + pgrp];              \
        lacc[0] = __builtin_amdgcn_mfma_f32_16x16x32_bf16(pf0_, ones, lacc[0], 0, 0, 0); \
        lacc[1] = __builtin_amdgcn_mfma_f32_16x16x32_bf16(pf1_, ones, lacc[1], 0, 0, 0); \
        __builtin_amdgcn_s_setprio(1);                                        \
        _Pragma("unroll")                                                     \
        for (int ns = 0; ns < 8; ++ns) {                                      \
            oacc[0][ns] = __builtin_amdgcn_mfma_f32_16x16x32_bf16(pf0_, VB[ns], oacc[0][ns], 0, 0, 0); \
            oacc[1][ns] = __builtin_amdgcn_mfma_f32_16x16x32_bf16(pf1_, VB[ns], oacc[1][ns], 0, 0, 0); \
        }                                                                     \
        __builtin_amdgcn_s_setprio(0);                                        \
    } while (0)

    LOADKV(ka, va, 0);
    int kt = 0;
    for (;;) {
        if (kt < qt) LOADKV(kb, vb, kt + 1);
        COMPUTE(ka, va, kt);
        if (++kt > qt) break;
        if (kt < qt) LOADKV(ka, va, kt + 1);
        COMPUTE(kb, vb, kt);
        if (++kt > qt) break;
    }

    // ---- epilogue: normalize, LDS transpose, coalesced 16 B stores ----
    float inv[2][4];
#pragma unroll
    for (int t = 0; t < 2; ++t)
#pragma unroll
        for (int g = 0; g < 4; ++g) inv[t][g] = 1.0f / lacc[t][g];

#pragma unroll
    for (int t = 0; t < 2; ++t)
#pragma unroll
        for (int g = 0; g < 4; ++g) {
            const int row = t * 16 + quad * 4 + g;
#pragma unroll
            for (int ns = 0; ns < 8; ++ns)
                Os[w][row][ns * 16 + r] = (bf16_t)(oacc[t][ns][g] * inv[t][g]);
        }

    bf16_t* ob = (bf16_t*)O + (size_t)(b * S_ + q0) * 2048 + h * D_;
#pragma unroll
    for (int c = 0; c < 8; ++c) {
        const int idx2 = c * 64 + lane;
        const int row = idx2 >> 4;
        const int seg = idx2 & 15;
        bf16x8 v8 = *(const bf16x8*)&Os[w][row][seg * 8];
        *(bf16x8*)(ob + (size_t)row * 2048 + seg * 8) = v8;
    }
#undef LOADKV
#undef COMPUTE
}

// ---------------------------------------------------------------------------
// Flash attention v3 (kept for the fallback path).
// ---------------------------------------------------------------------------
#define KT_ 32
#define LDK 136

__global__ __launch_bounds__(256, 2) void attn_flash3(const __hip_bfloat16* __restrict__ Q,
                                                      const __hip_bfloat16* __restrict__ K,
                                                      const __hip_bfloat16* __restrict__ V,
                                                      __hip_bfloat16* __restrict__ O,
                                                      int ldq, int ldkv, int ldo) {
    __shared__ unsigned short Ks[KT_][LDK];        // 8704 B
    __shared__ unsigned int Vt[D_ * 16];           // 8192 B (pair-packed)
    __shared__ unsigned int Pb[4][2][16][16];      // 8192 B (pair-packed)

    const int tid = threadIdx.x;
    const int w = tid >> 6;
    const int lane = tid & 63;
    const int r = lane & 15;
    const int quad = lane >> 4;

    const int gy = blockIdx.y;                     // b*HKV + kvh
    const int kvh = gy % HKV_;
    const int b = gy / HKV_;
    const int qt = b ? blockIdx.x : (gridDim.x - 1 - blockIdx.x);
    const int q0 = qt * 32;
    const int h = kvh * 4 + w;

    bf16x8 qf[2][4];
#pragma unroll
    for (int t = 0; t < 2; ++t) {
        const bf16_t* qp = (const bf16_t*)Q + (size_t)(b * S_ + q0 + t * 16 + r) * ldq + h * D_ + quad * 8;
#pragma unroll
        for (int c = 0; c < 4; ++c) qf[t][c] = *(const bf16x8*)(qp + c * 32);
    }

    f32x4 oacc[2][8] = {};
    f32x4 lacc[2] = {};
    float m_i[2][4];
#pragma unroll
    for (int t = 0; t < 2; ++t)
#pragma unroll
        for (int g = 0; g < 4; ++g) m_i[t][g] = -3e38f;

    const bf16_t* Kg = (const bf16_t*)K + (size_t)b * S_ * ldkv + kvh * D_;
    const bf16_t* Vg = (const bf16_t*)V + (size_t)b * S_ * ldkv + kvh * D_;

    bf16x8 ones;
#pragma unroll
    for (int j = 0; j < 8; ++j) ones[j] = (bf16_t)1.0f;

    const float SC2 = 0.08838834764831845f * 1.4426950408889634f;

    const int skey = tid >> 4;
    const int sdc = tid & 15;
    union U4 { uint4 u; unsigned short s[8]; };
    U4 rk0, rk1, rv0, rv1;
    {
        const size_t o0 = (size_t)skey * ldkv + sdc * 8;
        const size_t o1 = o0 + (size_t)16 * ldkv;
        rk0.u = *(const uint4*)(Kg + o0);
        rk1.u = *(const uint4*)(Kg + o1);
        rv0.u = *(const uint4*)(Vg + o0);
        rv1.u = *(const uint4*)(Vg + o1);
    }

    for (int kt = 0; kt <= qt; ++kt) {
        const int k0 = kt * KT_;
        __syncthreads();
        *(uint4*)&Ks[skey][sdc * 8] = rk0.u;
        *(uint4*)&Ks[skey + 16][sdc * 8] = rk1.u;
#pragma unroll
        for (int j = 0; j < 8; ++j) {
            const int d = sdc * 8 + j;
            const int f = ((j >> 1) & 3) ^ (sdc & 3);
            const int grp = (skey >> 2) ^ f;
            Vt[d * 16 + grp * 4 + (skey & 3)] = (unsigned)rv0.s[j] | ((unsigned)rv1.s[j] << 16);
        }
        __syncthreads();
        if (kt < qt) {
            const size_t o0 = (size_t)(k0 + KT_ + skey) * ldkv + sdc * 8;
            const size_t o1 = o0 + (size_t)16 * ldkv;
            rk0.u = *(const uint4*)(Kg + o0);
            rk1.u = *(const uint4*)(Kg + o1);
            rv0.u = *(const uint4*)(Vg + o0);
            rv1.u = *(const uint4*)(Vg + o1);
        }

        f32x4 s0[2] = {}, s1[2] = {};
#pragma unroll
        for (int c = 0; c < 4; ++c) {
            bf16x8 kb0 = *(const bf16x8*)&Ks[r][c * 32 + quad * 8];
            bf16x8 kb1 = *(const bf16x8*)&Ks[16 + r][c * 32 + quad * 8];
#pragma unroll
            for (int t = 0; t < 2; ++t) {
                s0[t] = __builtin_amdgcn_mfma_f32_16x16x32_bf16(qf[t][c], kb0, s0[t], 0, 0, 0);
                s1[t] = __builtin_amdgcn_mfma_f32_16x16x32_bf16(qf[t][c], kb1, s1[t], 0, 0, 0);
            }
        }

        const bool bnd = (kt == qt);
#pragma unroll
        for (int t = 0; t < 2; ++t) {
            float mt[4];
#pragma unroll
            for (int g = 0; g < 4; ++g) {
                s0[t][g] *= SC2;
                s1[t][g] *= SC2;
                if (bnd) {
                    const int qrow = q0 + t * 16 + quad * 4 + g;
                    if (k0 + r > qrow)      s0[t][g] = -1e38f;
                    if (k0 + 16 + r > qrow) s1[t][g] = -1e38f;
                }
                mt[g] = fmaxf(s0[t][g], s1[t][g]);
            }
#pragma unroll
            for (int msk = 1; msk < 16; msk <<= 1) {
#pragma unroll
                for (int g = 0; g < 4; ++g) mt[g] = fmaxf(mt[g], __shfl_xor(mt[g], msk, 64));
            }
            bool upd = false;
#pragma unroll
            for (int g = 0; g < 4; ++g) upd |= (mt[g] > m_i[t][g]);
            if (__ballot(upd)) {
#pragma unroll
                for (int g = 0; g < 4; ++g) {
                    const float mn = fmaxf(m_i[t][g], mt[g]);
                    const float al = exp2f(m_i[t][g] - mn);
                    m_i[t][g] = mn;
                    lacc[t][g] *= al;
#pragma unroll
                    for (int ns = 0; ns < 8; ++ns) oacc[t][ns][g] *= al;
                }
            }
#pragma unroll
            for (int g = 0; g < 4; ++g) {
                const float p0 = exp2f(s0[t][g] - m_i[t][g]);
                const float p1 = exp2f(s1[t][g] - m_i[t][g]);
                const int row = quad * 4 + g;
                Pb[w][t][row][(((r >> 2) ^ quad) & 3) * 4 + (r & 3)] = packbf2(p0, p1);
            }
        }

        const int pgrp = ((quad ^ (r >> 2)) & 3) * 4;
        bf16x8 pf0 = *(const bf16x8*)&Pb[w][0][r][pgrp];
        bf16x8 pf1 = *(const bf16x8*)&Pb[w][1][r][pgrp];

        lacc[0] = __builtin_amdgcn_mfma_f32_16x16x32_bf16(pf0, ones, lacc[0], 0, 0, 0);
        lacc[1] = __builtin_amdgcn_mfma_f32_16x16x32_bf16(pf1, ones, lacc[1], 0, 0, 0);

#pragma unroll
        for (int ns = 0; ns < 8; ++ns) {
            const int d = ns * 16 + r;
            const int f = ((r >> 1) & 3) ^ ((2 * ns + (r >> 3)) & 3);
            bf16x8 vf = *(const bf16x8*)&Vt[d * 16 + ((quad ^ f) & 3) * 4];
            oacc[0][ns] = __builtin_amdgcn_mfma_f32_16x16x32_bf16(pf0, vf, oacc[0][ns], 0, 0, 0);
            oacc[1][ns] = __builtin_amdgcn_mfma_f32_16x16x32_bf16(pf1, vf, oacc[1][ns], 0, 0, 0);
        }
    }

#pragma unroll
    for (int t = 0; t < 2; ++t) {
#pragma unroll
        for (int g = 0; g < 4; ++g) {
            const float inv = 1.0f / lacc[t][g];
            const int qrow = q0 + t * 16 + quad * 4 + g;
            __hip_bfloat16* op = O + (size_t)(b * S_ + qrow) * ldo + h * D_;
#pragma unroll
            for (int ns = 0; ns < 8; ++ns)
                op[ns * 16 + r] = __float2bfloat16(oacc[t][ns][g] * inv);
        }
    }
}

// ---------------------------------------------------------------------------
extern "C" void kernel_launch(void* const* d_in, const int* in_sizes, int n_in,
                              void* d_out, int out_size, void* d_ws, size_t ws_size,
                              hipStream_t stream) {
    const void* x    = d_in[0];
    const void* cosp = d_in[1];
    const void* sinp = d_in[2];
    const void* Wq   = d_in[3];
    const void* Wk   = d_in[4];
    const void* Wv   = d_in[5];
    const void* Wo   = d_in[6];

    const int M = B_ * S_;                 // 4096
    const size_t MB = 1ull << 20;

    if (ws_size >= 28 * MB + 64) {
        // Fast path. ws: [0,16M)=xb then ao; [16M,28M)=Wqkv, then Wo at [16M,24M)
        // and packed-V at [24M,28M); flag at 28M.
        // d_out: qkv bf16 [4096,3072] (24 MB), packed-K at [24M,28M), then output.
        char* ws = (char*)d_ws;
        bf16_t* xb = (bf16_t*)ws;
        bf16_t* wb = (bf16_t*)(ws + 16 * MB);
        bf16_t* wo = (bf16_t*)(ws + 16 * MB);
        unsigned* vp4 = (unsigned*)(ws + 24 * MB);
        bf16_t* ao = (bf16_t*)ws;
        int* flag  = (int*)(ws + 28 * MB);
        bf16_t* qkv = (bf16_t*)d_out;
        bf16_t* kp8 = (bf16_t*)((char*)d_out + 24 * MB);

        detect_dtype<<<1, 64, 0, stream>>>((const unsigned*)x, flag);

        // convert x, Wq, Wk, Wv -> bf16 (Wqkv contiguous [3072, 2048])
        Cseg sx{x,  xb,                          (B_ * S_ * HID_) / 8};
        Cseg sq{Wq, wb,                          (H_ * D_ * HID_) / 8};
        Cseg sk{Wk, wb + (size_t)2048 * HID_,    (HKV_ * D_ * HID_) / 8};
        Cseg sv{Wv, wb + (size_t)2560 * HID_,    (HKV_ * D_ * HID_) / 8};
        convert_bf16<<<dim3(4096, 4), 256, 0, stream>>>(sx, sq, sk, sv, flag);

        // Fused QKV projection: [4096,2048] x [3072,2048]^T -> qkv [4096,3072]
        gemm_lds<<<dim3(3072 / 128, M / 128), 256, 0, stream>>>(xb, wb, qkv, M, 3072, HID_, flag, 0);

        // convert Wo -> bf16 (wb dead; wo overlays wb)
        Cseg so{Wo, wo, (HID_ * H_ * D_) / 8};
        convert_bf16<<<dim3(2048, 1), 256, 0, stream>>>(so, so, so, so, flag);

        // pack V (no RoPE on V): qkv cols [2560,3072) -> vp4
        v_pack<<<(B_ * HKV_ * D_ * 64 * 16) / 256, 256, 0, stream>>>(
            (const __hip_bfloat16*)(qkv + 2560), vp4, 3072);

        // RoPE + RMSNorm in-place: q cols [0,2048), k cols [2048,2560)
        rope_rms<<<(B_ * S_ * H_) / 4, 256, 0, stream>>>((__hip_bfloat16*)qkv, cosp, sinp, H_, 3072, flag);
        rope_rms<<<(B_ * S_ * HKV_) / 4, 256, 0, stream>>>((__hip_bfloat16*)(qkv + 2048), cosp, sinp, HKV_, 3072, flag);

        // pack post-RoPE K into per-tile-contiguous layout
        k_pack<<<dim3(1024), 256, 0, stream>>>((const __hip_bfloat16*)(qkv + 2048), kp8);

        // Flash attention v6: Q strided in qkv, K/V packed; O -> ao (xb dead)
        attn_flash6<<<dim3(256), 512, 0, stream>>>(
            (const __hip_bfloat16*)qkv, kp8, vp4, (__hip_bfloat16*)ao);

        // Output projection: ao x Wo^T -> d_out (fp32 if flag=0)
        gemm_lds<<<dim3(HID_ / 128, M / 128), 256, 0, stream>>>(ao, wo, d_out, M, HID_, H_ * D_, flag, 1);
    } else {
        // Fallback: proven path (ws >= 16 MB + 4).
        __hip_bfloat16* qb = (__hip_bfloat16*)d_ws;
        int* flag = (int*)((char*)d_ws + (size_t)M * (H_ * D_) * sizeof(__hip_bfloat16));
        __hip_bfloat16* kb = (__hip_bfloat16*)d_out;
        __hip_bfloat16* vb = kb + (size_t)M * (HKV_ * D_);

        detect_dtype<<<1, 64, 0, stream>>>((const unsigned*)x, flag);

        gemm_bt<<<dim3((H_ * D_) / 64, M / 64), 256, 0, stream>>>(x, Wq, qb, M, H_ * D_, HID_, flag, 0);
        gemm_bt<<<dim3((HKV_ * D_) / 64, M / 64), 256, 0, stream>>>(x, Wk, kb, M, HKV_ * D_, HID_, flag, 0);
        gemm_bt<<<dim3((HKV_ * D_) / 64, M / 64), 256, 0, stream>>>(x, Wv, vb, M, HKV_ * D_, HID_, flag, 0);

        rope_rms<<<(B_ * S_ * H_) / 4, 256, 0, stream>>>(qb, cosp, sinp, H_, H_ * D_, flag);
        rope_rms<<<(B_ * S_ * HKV_) / 4, 256, 0, stream>>>(kb, cosp, sinp, HKV_, HKV_ * D_, flag);

        attn_flash3<<<dim3(S_ / 32, B_ * HKV_), 256, 0, stream>>>(qb, kb, vb, qb, H_ * D_, HKV_ * D_, H_ * D_);

        gemm_bt<<<dim3(HID_ / 64, M / 64), 256, 0, stream>>>(qb, Wo, d_out, M, HID_, H_ * D_, flag, 1);
    }
}

// Round 5
// 401.029 us; speedup vs baseline: 1.3466x; 1.3466x over previous
//
#include <hip/hip_runtime.h>
#include <hip/hip_bf16.h>

// Problem constants
#define B_  2
#define S_  2048
#define HID_ 2048
#define H_  16
#define HKV_ 4
#define D_  128

typedef __bf16 bf16_t;
typedef bf16_t bf16x8 __attribute__((ext_vector_type(8)));
typedef float f32x4 __attribute__((ext_vector_type(4)));

typedef __attribute__((address_space(3))) unsigned int lds_u32_t;
typedef const __attribute__((address_space(1))) unsigned int glob_u32_t;

// async global->LDS, 16 B per lane; LDS dest = wave-uniform base + lane*16
__device__ __forceinline__ void gl2lds16(const bf16_t* g, bf16_t* l) {
    __builtin_amdgcn_global_load_lds((glob_u32_t*)g, (lds_u32_t*)l, 16, 0, 0);
}

__device__ __forceinline__ unsigned packbf2(float a, float b) {
    union { bf16_t h[2]; unsigned u; } p;
    p.h[0] = (bf16_t)a;
    p.h[1] = (bf16_t)b;
    return p.u;
}

// ---------------------------------------------------------------------------
// Runtime dtype detection: flag=1 if inputs are bf16, 0 if fp32.
// ---------------------------------------------------------------------------
__global__ void detect_dtype(const unsigned* __restrict__ x, int* __restrict__ flag) {
    int lane = threadIdx.x;
    int c = 0;
#pragma unroll
    for (int i = 0; i < 16; ++i) {
        unsigned w = x[lane * 16 + i];
        unsigned e = (w >> 7) & 0xFF;
        c += (e >= 117 && e <= 137) ? 1 : 0;
    }
#pragma unroll
    for (int m = 1; m < 64; m <<= 1) c += __shfl_xor(c, m, 64);
    if (lane == 0) *flag = (c >= 512) ? 1 : 0;
}

// ---------------------------------------------------------------------------
// Conversion pass: src (fp32 or bf16 per flag) -> bf16 dst. 8 elems/thread.
// ---------------------------------------------------------------------------
struct Cseg { const void* src; bf16_t* dst; int n8; };

__global__ __launch_bounds__(256) void convert_bf16(Cseg s0, Cseg s1, Cseg s2, Cseg s3,
                                                    const int* __restrict__ flagp) {
    Cseg s = (blockIdx.y == 0) ? s0 : (blockIdx.y == 1) ? s1 : (blockIdx.y == 2) ? s2 : s3;
    const int i = blockIdx.x * 256 + threadIdx.x;
    if (i >= s.n8) return;
    if (*flagp) {
        ((uint4*)s.dst)[i] = ((const uint4*)s.src)[i];
    } else {
        const float4* p = (const float4*)s.src + (size_t)i * 2;
        float4 u = p[0], v = p[1];
        bf16x8 r;
        r[0] = (bf16_t)u.x; r[1] = (bf16_t)u.y; r[2] = (bf16_t)u.z; r[3] = (bf16_t)u.w;
        r[4] = (bf16_t)v.x; r[5] = (bf16_t)v.y; r[6] = (bf16_t)v.z; r[7] = (bf16_t)v.w;
        *(bf16x8*)(s.dst + (size_t)i * 8) = r;
    }
}

// ---------------------------------------------------------------------------
// m97-structure GEMM: C[m,n] = sum_k A[m,k]*W[n,k], A/W bf16 row-major.
// 128x128 tile, BK=32, LDS staging via global_load_lds width=16.
// ---------------------------------------------------------------------------
__global__ __launch_bounds__(256) void gemm_lds(const bf16_t* __restrict__ A,
                                                const bf16_t* __restrict__ W,
                                                void* __restrict__ C,
                                                int M, int N, int K,
                                                const int* __restrict__ flagp, int osel) {
    __shared__ bf16_t As[128 * 32];
    __shared__ bf16_t Bs[128 * 32];

    const int tid = threadIdx.x;
    const int w = tid >> 6;
    const int lane = tid & 63;
    const int r = lane & 15;
    const int quad = lane >> 4;
    const int m0 = blockIdx.y * 128;
    const int n0 = blockIdx.x * 128;
    const bool of32 = osel && (*flagp == 0);

    const int mh = (w & 1) * 64;
    const int nh = (w >> 1) * 64;

    const int c0 = w * 2;
    const int srow = lane >> 2;
    const int scol = (lane & 3) * 8;
    const bf16_t* Ag0 = A + (size_t)(m0 + c0 * 16 + srow) * K + scol;
    const bf16_t* Ag1 = A + (size_t)(m0 + c0 * 16 + 16 + srow) * K + scol;
    const bf16_t* Wg0 = W + (size_t)(n0 + c0 * 16 + srow) * K + scol;
    const bf16_t* Wg1 = W + (size_t)(n0 + c0 * 16 + 16 + srow) * K + scol;
    bf16_t* Al0 = As + c0 * 512;
    bf16_t* Al1 = As + (c0 + 1) * 512;
    bf16_t* Bl0 = Bs + c0 * 512;
    bf16_t* Bl1 = Bs + (c0 + 1) * 512;

    f32x4 acc[4][4] = {};

    for (int k0 = 0; k0 < K; k0 += 32) {
        __syncthreads();
        gl2lds16(Ag0 + k0, Al0);
        gl2lds16(Ag1 + k0, Al1);
        gl2lds16(Wg0 + k0, Bl0);
        gl2lds16(Wg1 + k0, Bl1);
        __syncthreads();

        bf16x8 a[4], b[4];
#pragma unroll
        for (int mi = 0; mi < 4; ++mi)
            a[mi] = *(const bf16x8*)&As[(mh + mi * 16 + r) * 32 + quad * 8];
#pragma unroll
        for (int ni = 0; ni < 4; ++ni)
            b[ni] = *(const bf16x8*)&Bs[(nh + ni * 16 + r) * 32 + quad * 8];
#pragma unroll
        for (int mi = 0; mi < 4; ++mi)
#pragma unroll
            for (int ni = 0; ni < 4; ++ni)
                acc[mi][ni] = __builtin_amdgcn_mfma_f32_16x16x32_bf16(a[mi], b[ni], acc[mi][ni], 0, 0, 0);
    }

#pragma unroll
    for (int mi = 0; mi < 4; ++mi) {
#pragma unroll
        for (int ni = 0; ni < 4; ++ni) {
#pragma unroll
            for (int g = 0; g < 4; ++g) {
                const int row = m0 + mh + mi * 16 + quad * 4 + g;
                const int col = n0 + nh + ni * 16 + r;
                if (of32) ((float*)C)[(size_t)row * N + col] = acc[mi][ni][g];
                else ((__hip_bfloat16*)C)[(size_t)row * N + col] = __float2bfloat16(acc[mi][ni][g]);
            }
        }
    }
}

// ---------------------------------------------------------------------------
// Fallback direct-from-global GEMM (proven path).
// ---------------------------------------------------------------------------
template <bool F32>
__device__ __forceinline__ bf16x8 load8(const void* base, size_t off) {
    bf16x8 r;
    if constexpr (F32) {
        const float4* p = (const float4*)((const float*)base + off);
        float4 u = p[0], v = p[1];
        r[0] = (bf16_t)u.x; r[1] = (bf16_t)u.y; r[2] = (bf16_t)u.z; r[3] = (bf16_t)u.w;
        r[4] = (bf16_t)v.x; r[5] = (bf16_t)v.y; r[6] = (bf16_t)v.z; r[7] = (bf16_t)v.w;
    } else {
        r = *(const bf16x8*)((const bf16_t*)base + off);
    }
    return r;
}

template <bool AF32, bool WF32, bool OF32>
__device__ __forceinline__ void gemm_body(const void* __restrict__ A, const void* __restrict__ W,
                                          void* __restrict__ C, int M, int N, int K) {
    const int wave = threadIdx.x >> 6;
    const int lane = threadIdx.x & 63;
    const int r = lane & 15;
    const int quad = lane >> 4;
    const int m0 = blockIdx.y * 64 + wave * 16;
    const int n0 = blockIdx.x * 64;

    f32x4 acc[4] = {};
    const size_t aoff = (size_t)(m0 + r) * K + quad * 8;
    const size_t woff = (size_t)(n0 + r) * K + quad * 8;

    for (int k0 = 0; k0 < K; k0 += 32) {
        bf16x8 a = load8<AF32>(A, aoff + k0);
#pragma unroll
        for (int ns = 0; ns < 4; ++ns) {
            bf16x8 b = load8<WF32>(W, woff + (size_t)(ns * 16) * K + k0);
            acc[ns] = __builtin_amdgcn_mfma_f32_16x16x32_bf16(a, b, acc[ns], 0, 0, 0);
        }
    }

#pragma unroll
    for (int ns = 0; ns < 4; ++ns) {
#pragma unroll
        for (int reg = 0; reg < 4; ++reg) {
            int m = m0 + quad * 4 + reg;
            int n = n0 + ns * 16 + r;
            if constexpr (OF32) ((float*)C)[(size_t)m * N + n] = acc[ns][reg];
            else ((__hip_bfloat16*)C)[(size_t)m * N + n] = __float2bfloat16(acc[ns][reg]);
        }
    }
}

__global__ __launch_bounds__(256) void gemm_bt(const void* __restrict__ A, const void* __restrict__ W,
                                               void* __restrict__ C, int M, int N, int K,
                                               const int* __restrict__ flagp, int mode) {
    const int bf = *flagp;
    if (bf) {
        gemm_body<false, false, false>(A, W, C, M, N, K);
    } else if (mode == 0) {
        gemm_body<true, true, false>(A, W, C, M, N, K);
    } else {
        gemm_body<false, true, true>(A, W, C, M, N, K);
    }
}

// ---------------------------------------------------------------------------
// In-place RoPE + RMSNorm on bf16 rows. Row (bs,h) at base + bs*ld + h*D.
// ---------------------------------------------------------------------------
__global__ __launch_bounds__(256) void rope_rms(__hip_bfloat16* __restrict__ qk,
                                                const void* __restrict__ cosp,
                                                const void* __restrict__ sinp,
                                                int NH, int ld, const int* __restrict__ flagp) {
    const int bf = *flagp;
    const int wave = threadIdx.x >> 6;
    const int lane = threadIdx.x & 63;
    const int row = blockIdx.x * 4 + wave;   // row = bs*NH + h
    const int h = row % NH;
    const int bs = row / NH;
    const int s = bs % S_;

    __hip_bfloat16* p = qk + (size_t)bs * ld + h * D_;
    float x1 = __bfloat162float(p[lane]);
    float x2 = __bfloat162float(p[lane + 64]);
    float c, sn, eps;
    if (bf) {
        c   = __bfloat162float(((const __hip_bfloat16*)cosp)[s * 64 + lane]);
        sn  = __bfloat162float(((const __hip_bfloat16*)sinp)[s * 64 + lane]);
        eps = 0.0078125f;
    } else {
        c   = ((const float*)cosp)[s * 64 + lane];
        sn  = ((const float*)sinp)[s * 64 + lane];
        eps = 1.1920929e-07f;
    }
    float y1 = x1 * c + x2 * sn;
    float y2 = x2 * c - x1 * sn;
    float ss = y1 * y1 + y2 * y2;
#pragma unroll
    for (int m = 1; m < 64; m <<= 1) ss += __shfl_xor(ss, m, 64);
    float rinv = rsqrtf(ss * (1.0f / 128.0f) + eps);
    p[lane]      = __float2bfloat16(y1 * rinv);
    p[lane + 64] = __float2bfloat16(y2 * rinv);
}

// ---------------------------------------------------------------------------
// K pack: post-RoPE K (strided in qkv) -> Kp[gy][kt][row32][d] bf16.
// Per (group, key-tile) the 32x128 tile is one contiguous 8 KB chunk.
// ---------------------------------------------------------------------------
__global__ __launch_bounds__(256) void k_pack(const __hip_bfloat16* __restrict__ Kin,
                                              bf16_t* __restrict__ Kp) {
    const int idx = blockIdx.x * 256 + threadIdx.x;   // 8 bf16 per thread
    const int d0 = (idx & 15) * 8;
    const int row = (idx >> 4) & 31;
    const int kt = (idx >> 9) & 63;
    const int gy = idx >> 15;
    const int kvh = gy & 3;
    const int bb = gy >> 2;
    const bf16_t* src = (const bf16_t*)Kin + (size_t)(bb * S_ + kt * 32 + row) * 3072 + kvh * D_ + d0;
    *(uint4*)(Kp + (size_t)idx * 8) = *(const uint4*)src;
}

// ---------------------------------------------------------------------------
// V pair-pack transpose: V[s][d] (strided in qkv) -> Vp[gy][kt][d][kp] u32
// where u32 = (V[32kt+kp][d], V[32kt+16+kp][d]).  kp = quad*4 + word is the
// fragment pair order the Pb path produces.
// ---------------------------------------------------------------------------
__global__ __launch_bounds__(256) void v_pack(const __hip_bfloat16* __restrict__ V,
                                              unsigned* __restrict__ Vp, int ldv) {
    const int idx = blockIdx.x * 256 + threadIdx.x;
    const int kp = idx & 15;
    const int d  = (idx >> 4) & 127;
    const int kt = (idx >> 11) & 63;
    const int gy = idx >> 17;                 // b*HKV + kvh
    const int kvh = gy & 3;
    const int b = gy >> 2;
    const unsigned short* p = (const unsigned short*)V
        + (size_t)(b * S_ + 32 * kt + kp) * ldv + kvh * D_ + d;
    unsigned lo = p[0];
    unsigned hi = p[(size_t)16 * ldv];
    Vp[idx] = lo | (hi << 16);
}

// ---------------------------------------------------------------------------
// Flash attention v7: v6's decorrelated structure, sized to the register file.
//
// v6 post-mortem: __launch_bounds__(512,2) imposed a 128-VGPR cap; the
// kernel needs ~240 -> ~110 regs/lane spilled, WRITE_SIZE 500 MB of scratch
// traffic, 281 us.  The pipeline wasn't disproven; it was spilled to death.
//
// v7 changes vs v6:
//  - __launch_bounds__(512) (no reg cap; actual ~230 -> 2 waves/SIMD, 0 spill)
//  - K double-buffered (64 regs); V single-buffered, its 8 loads issued at
//    the TOP of each iteration so ~250cy L2 latency hides under QK^T +
//    softmax + Pb round-trip; K[kt+1] issues after K[kt]'s MFMAs.
//  - scalar O epilogue (proven 16 MB WRITE in v4); LDS = Pb 16 KB only.
// Kept (hardware-verified): zero barriers, complementary per-SIMD balance
// (65 iters/SIMD exact), packed K/V, fixed-max softmax, setprio, XCD pin.
// Grid 256 x 512 thr.
// ---------------------------------------------------------------------------
#define M0F 16.5f

__global__ __launch_bounds__(512) void attn_flash7(const __hip_bfloat16* __restrict__ Q,
                                                   const bf16_t* __restrict__ Kp,
                                                   const unsigned* __restrict__ Vp,
                                                   __hip_bfloat16* __restrict__ O) {
    __shared__ unsigned PbS[8][2][16][16];   // 16 KB, wave-private P pair-pack

    const int tid = threadIdx.x;
    const int w = tid >> 6;
    const int lane = tid & 63;
    const int r = lane & 15;
    const int quad = lane >> 4;

    const int id = blockIdx.x;
    const int gy = id & 7;                  // group -> XCD pin
    const int u = id >> 3;
    const int hh = u & 3;
    const int i = u >> 2;                   // 0..7
    const int kvh = gy & 3;
    const int b = gy >> 2;
    const int h = kvh * 4 + hh;

    // Complementary tile table: waves w=0..3 get {i, 31-i, 16+i, 15-i};
    // waves w+4 get 63 - that.  Covers 0..63 exactly across i=0..7; SIMD
    // (w&3) hosts w and w^4 -> per-SIMD work = 65 key-tiles, exact balance.
    const int s4 = w & 3;
    int tlo = (s4 == 0) ? i : (s4 == 1) ? (31 - i) : (s4 == 2) ? (16 + i) : (15 - i);
    const int qt = (w < 4) ? tlo : (63 - tlo);
    const int q0 = qt * 32;

    const bf16_t* Kg = Kp + (size_t)gy * (64 * 32 * 128);
    const unsigned* Vg = Vp + (size_t)gy * (64 * 128 * 16);

    // Q fragments
    bf16x8 qf[2][4];
#pragma unroll
    for (int t = 0; t < 2; ++t) {
        const bf16_t* qp = (const bf16_t*)Q + (size_t)(b * S_ + q0 + t * 16 + r) * 3072 + h * D_ + quad * 8;
#pragma unroll
        for (int c = 0; c < 4; ++c) qf[t][c] = *(const bf16x8*)(qp + c * 32);
    }

    f32x4 oacc[2][8] = {};
    f32x4 lacc[2] = {};

    bf16x8 ones;
#pragma unroll
    for (int j = 0; j < 8; ++j) ones[j] = (bf16_t)1.0f;

    const float SC2 = 0.08838834764831845f * 1.4426950408889634f;  // D^-0.5 * log2(e)

    unsigned* pbw = &PbS[w][0][0][0];
    const int pwi = (((r >> 2) ^ quad) & 3) * 4 + (r & 3);   // write slot
    const int pgrp = ((quad ^ (r >> 2)) & 3) * 4;            // read group

    bf16x8 ka[8], kb[8], va[8];

#define LOADK(KB, KT) do {                                                    \
        const bf16_t* kp_ = Kg + (size_t)(KT) * 4096 + r * 128 + quad * 8;    \
        KB[0] = *(const bf16x8*)(kp_);                                        \
        KB[1] = *(const bf16x8*)(kp_ + 2048);                                 \
        KB[2] = *(const bf16x8*)(kp_ + 32);                                   \
        KB[3] = *(const bf16x8*)(kp_ + 2048 + 32);                            \
        KB[4] = *(const bf16x8*)(kp_ + 64);                                   \
        KB[5] = *(const bf16x8*)(kp_ + 2048 + 64);                            \
        KB[6] = *(const bf16x8*)(kp_ + 96);                                   \
        KB[7] = *(const bf16x8*)(kp_ + 2048 + 96);                            \
    } while (0)

#define LOADV(KT) do {                                                        \
        const unsigned* vp_ = Vg + (size_t)(KT) * 2048 + r * 16 + quad * 4;   \
        va[0] = *(const bf16x8*)(vp_);                                        \
        va[1] = *(const bf16x8*)(vp_ + 256);                                  \
        va[2] = *(const bf16x8*)(vp_ + 512);                                  \
        va[3] = *(const bf16x8*)(vp_ + 768);                                  \
        va[4] = *(const bf16x8*)(vp_ + 1024);                                 \
        va[5] = *(const bf16x8*)(vp_ + 1280);                                 \
        va[6] = *(const bf16x8*)(vp_ + 1536);                                 \
        va[7] = *(const bf16x8*)(vp_ + 1792);                                 \
    } while (0)

#define STEP(KCUR, KNXT, KT) do {                                             \
        LOADV(KT);                                                            \
        f32x4 s0_[2] = {}, s1_[2] = {};                                       \
        __builtin_amdgcn_s_setprio(1);                                        \
        _Pragma("unroll")                                                     \
        for (int c = 0; c < 4; ++c) {                                         \
            _Pragma("unroll")                                                 \
            for (int t = 0; t < 2; ++t) {                                     \
                s0_[t] = __builtin_amdgcn_mfma_f32_16x16x32_bf16(qf[t][c], KCUR[c * 2], s0_[t], 0, 0, 0);     \
                s1_[t] = __builtin_amdgcn_mfma_f32_16x16x32_bf16(qf[t][c], KCUR[c * 2 + 1], s1_[t], 0, 0, 0); \
            }                                                                 \
        }                                                                     \
        __builtin_amdgcn_s_setprio(0);                                        \
        if ((KT) < qt) LOADK(KNXT, (KT) + 1);                                 \
        if ((KT) == qt) {                                                     \
            _Pragma("unroll")                                                 \
            for (int t = 0; t < 2; ++t)                                       \
                _Pragma("unroll")                                             \
                for (int g = 0; g < 4; ++g) {                                 \
                    const int qrow_ = q0 + t * 16 + quad * 4 + g;             \
                    if ((KT) * 32 + r > qrow_)      s0_[t][g] = -1e38f;       \
                    if ((KT) * 32 + 16 + r > qrow_) s1_[t][g] = -1e38f;       \
                }                                                             \
        }                                                                     \
        _Pragma("unroll")                                                     \
        for (int t = 0; t < 2; ++t)                                           \
            _Pragma("unroll")                                                 \
            for (int g = 0; g < 4; ++g) {                                     \
                const float p0_ = exp2f(fmaf(s0_[t][g], SC2, -M0F));          \
                const float p1_ = exp2f(fmaf(s1_[t][g], SC2, -M0F));          \
                pbw[t * 256 + (quad * 4 + g) * 16 + pwi] = packbf2(p0_, p1_); \
            }                                                                 \
        bf16x8 pf0_ = *(const bf16x8*)&pbw[r * 16 + pgrp];                    \
        bf16x8 pf1_ = *(const bf16x8*)&pbw[256 + r * 16 + pgrp];              \
        lacc[0] = __builtin_amdgcn_mfma_f32_16x16x32_bf16(pf0_, ones, lacc[0], 0, 0, 0); \
        lacc[1] = __builtin_amdgcn_mfma_f32_16x16x32_bf16(pf1_, ones, lacc[1], 0, 0, 0); \
        __builtin_amdgcn_s_setprio(1);                                        \
        _Pragma("unroll")                                                     \
        for (int ns = 0; ns < 8; ++ns) {                                      \
            oacc[0][ns] = __builtin_amdgcn_mfma_f32_16x16x32_bf16(pf0_, va[ns], oacc[0][ns], 0, 0, 0); \
            oacc[1][ns] = __builtin_amdgcn_mfma_f32_16x16x32_bf16(pf1_, va[ns], oacc[1][ns], 0, 0, 0); \
        }                                                                     \
        __builtin_amdgcn_s_setprio(0);                                        \
    } while (0)

    LOADK(ka, 0);
    int kt = 0;
    for (;;) {
        STEP(ka, kb, kt);
        if (++kt > qt) break;
        STEP(kb, ka, kt);
        if (++kt > qt) break;
    }
#undef LOADK
#undef LOADV
#undef STEP

    // ---- epilogue: normalize + scalar stores (proven 16 MB WRITE) ----
#pragma unroll
    for (int t = 0; t < 2; ++t) {
#pragma unroll
        for (int g = 0; g < 4; ++g) {
            const float inv = 1.0f / lacc[t][g];
            const int qrow = q0 + t * 16 + quad * 4 + g;
            __hip_bfloat16* op = O + (size_t)(b * S_ + qrow) * 2048 + h * D_;
#pragma unroll
            for (int ns = 0; ns < 8; ++ns)
                op[ns * 16 + r] = __float2bfloat16(oacc[t][ns][g] * inv);
        }
    }
}

// ---------------------------------------------------------------------------
// Flash attention v3 (kept for the fallback path).
// ---------------------------------------------------------------------------
#define KT_ 32
#define LDK 136

__global__ __launch_bounds__(256, 2) void attn_flash3(const __hip_bfloat16* __restrict__ Q,
                                                      const __hip_bfloat16* __restrict__ K,
                                                      const __hip_bfloat16* __restrict__ V,
                                                      __hip_bfloat16* __restrict__ O,
                                                      int ldq, int ldkv, int ldo) {
    __shared__ unsigned short Ks[KT_][LDK];        // 8704 B
    __shared__ unsigned int Vt[D_ * 16];           // 8192 B (pair-packed)
    __shared__ unsigned int Pb[4][2][16][16];      // 8192 B (pair-packed)

    const int tid = threadIdx.x;
    const int w = tid >> 6;
    const int lane = tid & 63;
    const int r = lane & 15;
    const int quad = lane >> 4;

    const int gy = blockIdx.y;                     // b*HKV + kvh
    const int kvh = gy % HKV_;
    const int b = gy / HKV_;
    const int qt = b ? blockIdx.x : (gridDim.x - 1 - blockIdx.x);
    const int q0 = qt * 32;
    const int h = kvh * 4 + w;

    bf16x8 qf[2][4];
#pragma unroll
    for (int t = 0; t < 2; ++t) {
        const bf16_t* qp = (const bf16_t*)Q + (size_t)(b * S_ + q0 + t * 16 + r) * ldq + h * D_ + quad * 8;
#pragma unroll
        for (int c = 0; c < 4; ++c) qf[t][c] = *(const bf16x8*)(qp + c * 32);
    }

    f32x4 oacc[2][8] = {};
    f32x4 lacc[2] = {};
    float m_i[2][4];
#pragma unroll
    for (int t = 0; t < 2; ++t)
#pragma unroll
        for (int g = 0; g < 4; ++g) m_i[t][g] = -3e38f;

    const bf16_t* Kg = (const bf16_t*)K + (size_t)b * S_ * ldkv + kvh * D_;
    const bf16_t* Vg = (const bf16_t*)V + (size_t)b * S_ * ldkv + kvh * D_;

    bf16x8 ones;
#pragma unroll
    for (int j = 0; j < 8; ++j) ones[j] = (bf16_t)1.0f;

    const float SC2 = 0.08838834764831845f * 1.4426950408889634f;

    const int skey = tid >> 4;
    const int sdc = tid & 15;
    union U4 { uint4 u; unsigned short s[8]; };
    U4 rk0, rk1, rv0, rv1;
    {
        const size_t o0 = (size_t)skey * ldkv + sdc * 8;
        const size_t o1 = o0 + (size_t)16 * ldkv;
        rk0.u = *(const uint4*)(Kg + o0);
        rk1.u = *(const uint4*)(Kg + o1);
        rv0.u = *(const uint4*)(Vg + o0);
        rv1.u = *(const uint4*)(Vg + o1);
    }

    for (int kt = 0; kt <= qt; ++kt) {
        const int k0 = kt * KT_;
        __syncthreads();
        *(uint4*)&Ks[skey][sdc * 8] = rk0.u;
        *(uint4*)&Ks[skey + 16][sdc * 8] = rk1.u;
#pragma unroll
        for (int j = 0; j < 8; ++j) {
            const int d = sdc * 8 + j;
            const int f = ((j >> 1) & 3) ^ (sdc & 3);
            const int grp = (skey >> 2) ^ f;
            Vt[d * 16 + grp * 4 + (skey & 3)] = (unsigned)rv0.s[j] | ((unsigned)rv1.s[j] << 16);
        }
        __syncthreads();
        if (kt < qt) {
            const size_t o0 = (size_t)(k0 + KT_ + skey) * ldkv + sdc * 8;
            const size_t o1 = o0 + (size_t)16 * ldkv;
            rk0.u = *(const uint4*)(Kg + o0);
            rk1.u = *(const uint4*)(Kg + o1);
            rv0.u = *(const uint4*)(Vg + o0);
            rv1.u = *(const uint4*)(Vg + o1);
        }

        f32x4 s0[2] = {}, s1[2] = {};
#pragma unroll
        for (int c = 0; c < 4; ++c) {
            bf16x8 kb0 = *(const bf16x8*)&Ks[r][c * 32 + quad * 8];
            bf16x8 kb1 = *(const bf16x8*)&Ks[16 + r][c * 32 + quad * 8];
#pragma unroll
            for (int t = 0; t < 2; ++t) {
                s0[t] = __builtin_amdgcn_mfma_f32_16x16x32_bf16(qf[t][c], kb0, s0[t], 0, 0, 0);
                s1[t] = __builtin_amdgcn_mfma_f32_16x16x32_bf16(qf[t][c], kb1, s1[t], 0, 0, 0);
            }
        }

        const bool bnd = (kt == qt);
#pragma unroll
        for (int t = 0; t < 2; ++t) {
            float mt[4];
#pragma unroll
            for (int g = 0; g < 4; ++g) {
                s0[t][g] *= SC2;
                s1[t][g] *= SC2;
                if (bnd) {
                    const int qrow = q0 + t * 16 + quad * 4 + g;
                    if (k0 + r > qrow)      s0[t][g] = -1e38f;
                    if (k0 + 16 + r > qrow) s1[t][g] = -1e38f;
                }
                mt[g] = fmaxf(s0[t][g], s1[t][g]);
            }
#pragma unroll
            for (int msk = 1; msk < 16; msk <<= 1) {
#pragma unroll
                for (int g = 0; g < 4; ++g) mt[g] = fmaxf(mt[g], __shfl_xor(mt[g], msk, 64));
            }
            bool upd = false;
#pragma unroll
            for (int g = 0; g < 4; ++g) upd |= (mt[g] > m_i[t][g]);
            if (__ballot(upd)) {
#pragma unroll
                for (int g = 0; g < 4; ++g) {
                    const float mn = fmaxf(m_i[t][g], mt[g]);
                    const float al = exp2f(m_i[t][g] - mn);
                    m_i[t][g] = mn;
                    lacc[t][g] *= al;
#pragma unroll
                    for (int ns = 0; ns < 8; ++ns) oacc[t][ns][g] *= al;
                }
            }
#pragma unroll
            for (int g = 0; g < 4; ++g) {
                const float p0 = exp2f(s0[t][g] - m_i[t][g]);
                const float p1 = exp2f(s1[t][g] - m_i[t][g]);
                const int row = quad * 4 + g;
                Pb[w][t][row][(((r >> 2) ^ quad) & 3) * 4 + (r & 3)] = packbf2(p0, p1);
            }
        }

        const int pgrp = ((quad ^ (r >> 2)) & 3) * 4;
        bf16x8 pf0 = *(const bf16x8*)&Pb[w][0][r][pgrp];
        bf16x8 pf1 = *(const bf16x8*)&Pb[w][1][r][pgrp];

        lacc[0] = __builtin_amdgcn_mfma_f32_16x16x32_bf16(pf0, ones, lacc[0], 0, 0, 0);
        lacc[1] = __builtin_amdgcn_mfma_f32_16x16x32_bf16(pf1, ones, lacc[1], 0, 0, 0);

#pragma unroll
        for (int ns = 0; ns < 8; ++ns) {
            const int d = ns * 16 + r;
            const int f = ((r >> 1) & 3) ^ ((2 * ns + (r >> 3)) & 3);
            bf16x8 vf = *(const bf16x8*)&Vt[d * 16 + ((quad ^ f) & 3) * 4];
            oacc[0][ns] = __builtin_amdgcn_mfma_f32_16x16x32_bf16(pf0, vf, oacc[0][ns], 0, 0, 0);
            oacc[1][ns] = __builtin_amdgcn_mfma_f32_16x16x32_bf16(pf1, vf, oacc[1][ns], 0, 0, 0);
        }
    }

#pragma unroll
    for (int t = 0; t < 2; ++t) {
#pragma unroll
        for (int g = 0; g < 4; ++g) {
            const float inv = 1.0f / lacc[t][g];
            const int qrow = q0 + t * 16 + quad * 4 + g;
            __hip_bfloat16* op = O + (size_t)(b * S_ + qrow) * ldo + h * D_;
#pragma unroll
            for (int ns = 0; ns < 8; ++ns)
                op[ns * 16 + r] = __float2bfloat16(oacc[t][ns][g] * inv);
        }
    }
}

// ---------------------------------------------------------------------------
extern "C" void kernel_launch(void* const* d_in, const int* in_sizes, int n_in,
                              void* d_out, int out_size, void* d_ws, size_t ws_size,
                              hipStream_t stream) {
    const void* x    = d_in[0];
    const void* cosp = d_in[1];
    const void* sinp = d_in[2];
    const void* Wq   = d_in[3];
    const void* Wk   = d_in[4];
    const void* Wv   = d_in[5];
    const void* Wo   = d_in[6];

    const int M = B_ * S_;                 // 4096
    const size_t MB = 1ull << 20;

    if (ws_size >= 28 * MB + 64) {
        // Fast path. ws: [0,16M)=xb then ao; [16M,28M)=Wqkv, then Wo at [16M,24M)
        // and packed-V at [24M,28M); flag at 28M.
        // d_out: qkv bf16 [4096,3072] (24 MB), packed-K at [24M,28M), then output.
        char* ws = (char*)d_ws;
        bf16_t* xb = (bf16_t*)ws;
        bf16_t* wb = (bf16_t*)(ws + 16 * MB);
        bf16_t* wo = (bf16_t*)(ws + 16 * MB);
        unsigned* vp4 = (unsigned*)(ws + 24 * MB);
        bf16_t* ao = (bf16_t*)ws;
        int* flag  = (int*)(ws + 28 * MB);
        bf16_t* qkv = (bf16_t*)d_out;
        bf16_t* kp8 = (bf16_t*)((char*)d_out + 24 * MB);

        detect_dtype<<<1, 64, 0, stream>>>((const unsigned*)x, flag);

        // convert x, Wq, Wk, Wv -> bf16 (Wqkv contiguous [3072, 2048])
        Cseg sx{x,  xb,                          (B_ * S_ * HID_) / 8};
        Cseg sq{Wq, wb,                          (H_ * D_ * HID_) / 8};
        Cseg sk{Wk, wb + (size_t)2048 * HID_,    (HKV_ * D_ * HID_) / 8};
        Cseg sv{Wv, wb + (size_t)2560 * HID_,    (HKV_ * D_ * HID_) / 8};
        convert_bf16<<<dim3(4096, 4), 256, 0, stream>>>(sx, sq, sk, sv, flag);

        // Fused QKV projection: [4096,2048] x [3072,2048]^T -> qkv [4096,3072]
        gemm_lds<<<dim3(3072 / 128, M / 128), 256, 0, stream>>>(xb, wb, qkv, M, 3072, HID_, flag, 0);

        // convert Wo -> bf16 (wb dead; wo overlays wb)
        Cseg so{Wo, wo, (HID_ * H_ * D_) / 8};
        convert_bf16<<<dim3(2048, 1), 256, 0, stream>>>(so, so, so, so, flag);

        // pack V (no RoPE on V): qkv cols [2560,3072) -> vp4
        v_pack<<<(B_ * HKV_ * D_ * 64 * 16) / 256, 256, 0, stream>>>(
            (const __hip_bfloat16*)(qkv + 2560), vp4, 3072);

        // RoPE + RMSNorm in-place: q cols [0,2048), k cols [2048,2560)
        rope_rms<<<(B_ * S_ * H_) / 4, 256, 0, stream>>>((__hip_bfloat16*)qkv, cosp, sinp, H_, 3072, flag);
        rope_rms<<<(B_ * S_ * HKV_) / 4, 256, 0, stream>>>((__hip_bfloat16*)(qkv + 2048), cosp, sinp, HKV_, 3072, flag);

        // pack post-RoPE K into per-tile-contiguous layout
        k_pack<<<dim3(1024), 256, 0, stream>>>((const __hip_bfloat16*)(qkv + 2048), kp8);

        // Flash attention v7: Q strided in qkv, K/V packed; O -> ao (xb dead)
        attn_flash7<<<dim3(256), 512, 0, stream>>>(
            (const __hip_bfloat16*)qkv, kp8, vp4, (__hip_bfloat16*)ao);

        // Output projection: ao x Wo^T -> d_out (fp32 if flag=0)
        gemm_lds<<<dim3(HID_ / 128, M / 128), 256, 0, stream>>>(ao, wo, d_out, M, HID_, H_ * D_, flag, 1);
    } else {
        // Fallback: proven path (ws >= 16 MB + 4).
        __hip_bfloat16* qb = (__hip_bfloat16*)d_ws;
        int* flag = (int*)((char*)d_ws + (size_t)M * (H_ * D_) * sizeof(__hip_bfloat16));
        __hip_bfloat16* kb = (__hip_bfloat16*)d_out;
        __hip_bfloat16* vb = kb + (size_t)M * (HKV_ * D_);

        detect_dtype<<<1, 64, 0, stream>>>((const unsigned*)x, flag);

        gemm_bt<<<dim3((H_ * D_) / 64, M / 64), 256, 0, stream>>>(x, Wq, qb, M, H_ * D_, HID_, flag, 0);
        gemm_bt<<<dim3((HKV_ * D_) / 64, M / 64), 256, 0, stream>>>(x, Wk, kb, M, HKV_ * D_, HID_, flag, 0);
        gemm_bt<<<dim3((HKV_ * D_) / 64, M / 64), 256, 0, stream>>>(x, Wv, vb, M, HKV_ * D_, HID_, flag, 0);

        rope_rms<<<(B_ * S_ * H_) / 4, 256, 0, stream>>>(qb, cosp, sinp, H_, H_ * D_, flag);
        rope_rms<<<(B_ * S_ * HKV_) / 4, 256, 0, stream>>>(kb, cosp, sinp, HKV_, HKV_ * D_, flag);

        attn_flash3<<<dim3(S_ / 32, B_ * HKV_), 256, 0, stream>>>(qb, kb, vb, qb, H_ * D_, HKV_ * D_, H_ * D_);

        gemm_bt<<<dim3(HID_ / 64, M / 64), 256, 0, stream>>>(qb, Wo, d_out, M, HID_, H_ * D_, flag, 1);
    }
}

// Round 6
// 400.120 us; speedup vs baseline: 1.3496x; 1.0023x over previous
//
#include <hip/hip_runtime.h>
#include <hip/hip_bf16.h>

// Problem constants
#define B_  2
#define S_  2048
#define HID_ 2048
#define H_  16
#define HKV_ 4
#define D_  128

typedef __bf16 bf16_t;
typedef bf16_t bf16x8 __attribute__((ext_vector_type(8)));
typedef float f32x4 __attribute__((ext_vector_type(4)));

typedef __attribute__((address_space(3))) unsigned int lds_u32_t;
typedef const __attribute__((address_space(1))) unsigned int glob_u32_t;

// async global->LDS, 16 B per lane; LDS dest = wave-uniform base + lane*16
__device__ __forceinline__ void gl2lds16(const bf16_t* g, bf16_t* l) {
    __builtin_amdgcn_global_load_lds((glob_u32_t*)g, (lds_u32_t*)l, 16, 0, 0);
}

__device__ __forceinline__ unsigned packbf2(float a, float b) {
    union { bf16_t h[2]; unsigned u; } p;
    p.h[0] = (bf16_t)a;
    p.h[1] = (bf16_t)b;
    return p.u;
}

// ---------------------------------------------------------------------------
// Runtime dtype detection: flag=1 if inputs are bf16, 0 if fp32.
// ---------------------------------------------------------------------------
__global__ void detect_dtype(const unsigned* __restrict__ x, int* __restrict__ flag) {
    int lane = threadIdx.x;
    int c = 0;
#pragma unroll
    for (int i = 0; i < 16; ++i) {
        unsigned w = x[lane * 16 + i];
        unsigned e = (w >> 7) & 0xFF;
        c += (e >= 117 && e <= 137) ? 1 : 0;
    }
#pragma unroll
    for (int m = 1; m < 64; m <<= 1) c += __shfl_xor(c, m, 64);
    if (lane == 0) *flag = (c >= 512) ? 1 : 0;
}

// ---------------------------------------------------------------------------
// Conversion pass: src (fp32 or bf16 per flag) -> bf16 dst. 8 elems/thread.
// ---------------------------------------------------------------------------
struct Cseg { const void* src; bf16_t* dst; int n8; };

__global__ __launch_bounds__(256) void convert_bf16(Cseg s0, Cseg s1, Cseg s2, Cseg s3,
                                                    const int* __restrict__ flagp) {
    Cseg s = (blockIdx.y == 0) ? s0 : (blockIdx.y == 1) ? s1 : (blockIdx.y == 2) ? s2 : s3;
    const int i = blockIdx.x * 256 + threadIdx.x;
    if (i >= s.n8) return;
    if (*flagp) {
        ((uint4*)s.dst)[i] = ((const uint4*)s.src)[i];
    } else {
        const float4* p = (const float4*)s.src + (size_t)i * 2;
        float4 u = p[0], v = p[1];
        bf16x8 r;
        r[0] = (bf16_t)u.x; r[1] = (bf16_t)u.y; r[2] = (bf16_t)u.z; r[3] = (bf16_t)u.w;
        r[4] = (bf16_t)v.x; r[5] = (bf16_t)v.y; r[6] = (bf16_t)v.z; r[7] = (bf16_t)v.w;
        *(bf16x8*)(s.dst + (size_t)i * 8) = r;
    }
}

// ---------------------------------------------------------------------------
// m97-structure GEMM: C[m,n] = sum_k A[m,k]*W[n,k], A/W bf16 row-major.
// 128x128 tile, BK=32, LDS staging via global_load_lds width=16.
// ---------------------------------------------------------------------------
__global__ __launch_bounds__(256) void gemm_lds(const bf16_t* __restrict__ A,
                                                const bf16_t* __restrict__ W,
                                                void* __restrict__ C,
                                                int M, int N, int K,
                                                const int* __restrict__ flagp, int osel) {
    __shared__ bf16_t As[128 * 32];
    __shared__ bf16_t Bs[128 * 32];

    const int tid = threadIdx.x;
    const int w = tid >> 6;
    const int lane = tid & 63;
    const int r = lane & 15;
    const int quad = lane >> 4;
    const int m0 = blockIdx.y * 128;
    const int n0 = blockIdx.x * 128;
    const bool of32 = osel && (*flagp == 0);

    const int mh = (w & 1) * 64;
    const int nh = (w >> 1) * 64;

    const int c0 = w * 2;
    const int srow = lane >> 2;
    const int scol = (lane & 3) * 8;
    const bf16_t* Ag0 = A + (size_t)(m0 + c0 * 16 + srow) * K + scol;
    const bf16_t* Ag1 = A + (size_t)(m0 + c0 * 16 + 16 + srow) * K + scol;
    const bf16_t* Wg0 = W + (size_t)(n0 + c0 * 16 + srow) * K + scol;
    const bf16_t* Wg1 = W + (size_t)(n0 + c0 * 16 + 16 + srow) * K + scol;
    bf16_t* Al0 = As + c0 * 512;
    bf16_t* Al1 = As + (c0 + 1) * 512;
    bf16_t* Bl0 = Bs + c0 * 512;
    bf16_t* Bl1 = Bs + (c0 + 1) * 512;

    f32x4 acc[4][4] = {};

    for (int k0 = 0; k0 < K; k0 += 32) {
        __syncthreads();
        gl2lds16(Ag0 + k0, Al0);
        gl2lds16(Ag1 + k0, Al1);
        gl2lds16(Wg0 + k0, Bl0);
        gl2lds16(Wg1 + k0, Bl1);
        __syncthreads();

        bf16x8 a[4], b[4];
#pragma unroll
        for (int mi = 0; mi < 4; ++mi)
            a[mi] = *(const bf16x8*)&As[(mh + mi * 16 + r) * 32 + quad * 8];
#pragma unroll
        for (int ni = 0; ni < 4; ++ni)
            b[ni] = *(const bf16x8*)&Bs[(nh + ni * 16 + r) * 32 + quad * 8];
#pragma unroll
        for (int mi = 0; mi < 4; ++mi)
#pragma unroll
            for (int ni = 0; ni < 4; ++ni)
                acc[mi][ni] = __builtin_amdgcn_mfma_f32_16x16x32_bf16(a[mi], b[ni], acc[mi][ni], 0, 0, 0);
    }

#pragma unroll
    for (int mi = 0; mi < 4; ++mi) {
#pragma unroll
        for (int ni = 0; ni < 4; ++ni) {
#pragma unroll
            for (int g = 0; g < 4; ++g) {
                const int row = m0 + mh + mi * 16 + quad * 4 + g;
                const int col = n0 + nh + ni * 16 + r;
                if (of32) ((float*)C)[(size_t)row * N + col] = acc[mi][ni][g];
                else ((__hip_bfloat16*)C)[(size_t)row * N + col] = __float2bfloat16(acc[mi][ni][g]);
            }
        }
    }
}

// ---------------------------------------------------------------------------
// Fallback direct-from-global GEMM (proven path).
// ---------------------------------------------------------------------------
template <bool F32>
__device__ __forceinline__ bf16x8 load8(const void* base, size_t off) {
    bf16x8 r;
    if constexpr (F32) {
        const float4* p = (const float4*)((const float*)base + off);
        float4 u = p[0], v = p[1];
        r[0] = (bf16_t)u.x; r[1] = (bf16_t)u.y; r[2] = (bf16_t)u.z; r[3] = (bf16_t)u.w;
        r[4] = (bf16_t)v.x; r[5] = (bf16_t)v.y; r[6] = (bf16_t)v.z; r[7] = (bf16_t)v.w;
    } else {
        r = *(const bf16x8*)((const bf16_t*)base + off);
    }
    return r;
}

template <bool AF32, bool WF32, bool OF32>
__device__ __forceinline__ void gemm_body(const void* __restrict__ A, const void* __restrict__ W,
                                          void* __restrict__ C, int M, int N, int K) {
    const int wave = threadIdx.x >> 6;
    const int lane = threadIdx.x & 63;
    const int r = lane & 15;
    const int quad = lane >> 4;
    const int m0 = blockIdx.y * 64 + wave * 16;
    const int n0 = blockIdx.x * 64;

    f32x4 acc[4] = {};
    const size_t aoff = (size_t)(m0 + r) * K + quad * 8;
    const size_t woff = (size_t)(n0 + r) * K + quad * 8;

    for (int k0 = 0; k0 < K; k0 += 32) {
        bf16x8 a = load8<AF32>(A, aoff + k0);
#pragma unroll
        for (int ns = 0; ns < 4; ++ns) {
            bf16x8 b = load8<WF32>(W, woff + (size_t)(ns * 16) * K + k0);
            acc[ns] = __builtin_amdgcn_mfma_f32_16x16x32_bf16(a, b, acc[ns], 0, 0, 0);
        }
    }

#pragma unroll
    for (int ns = 0; ns < 4; ++ns) {
#pragma unroll
        for (int reg = 0; reg < 4; ++reg) {
            int m = m0 + quad * 4 + reg;
            int n = n0 + ns * 16 + r;
            if constexpr (OF32) ((float*)C)[(size_t)m * N + n] = acc[ns][reg];
            else ((__hip_bfloat16*)C)[(size_t)m * N + n] = __float2bfloat16(acc[ns][reg]);
        }
    }
}

__global__ __launch_bounds__(256) void gemm_bt(const void* __restrict__ A, const void* __restrict__ W,
                                               void* __restrict__ C, int M, int N, int K,
                                               const int* __restrict__ flagp, int mode) {
    const int bf = *flagp;
    if (bf) {
        gemm_body<false, false, false>(A, W, C, M, N, K);
    } else if (mode == 0) {
        gemm_body<true, true, false>(A, W, C, M, N, K);
    } else {
        gemm_body<false, true, true>(A, W, C, M, N, K);
    }
}

// ---------------------------------------------------------------------------
// In-place RoPE + RMSNorm on bf16 rows. Row (bs,h) at base + bs*ld + h*D.
// ---------------------------------------------------------------------------
__global__ __launch_bounds__(256) void rope_rms(__hip_bfloat16* __restrict__ qk,
                                                const void* __restrict__ cosp,
                                                const void* __restrict__ sinp,
                                                int NH, int ld, const int* __restrict__ flagp) {
    const int bf = *flagp;
    const int wave = threadIdx.x >> 6;
    const int lane = threadIdx.x & 63;
    const int row = blockIdx.x * 4 + wave;   // row = bs*NH + h
    const int h = row % NH;
    const int bs = row / NH;
    const int s = bs % S_;

    __hip_bfloat16* p = qk + (size_t)bs * ld + h * D_;
    float x1 = __bfloat162float(p[lane]);
    float x2 = __bfloat162float(p[lane + 64]);
    float c, sn, eps;
    if (bf) {
        c   = __bfloat162float(((const __hip_bfloat16*)cosp)[s * 64 + lane]);
        sn  = __bfloat162float(((const __hip_bfloat16*)sinp)[s * 64 + lane]);
        eps = 0.0078125f;
    } else {
        c   = ((const float*)cosp)[s * 64 + lane];
        sn  = ((const float*)sinp)[s * 64 + lane];
        eps = 1.1920929e-07f;
    }
    float y1 = x1 * c + x2 * sn;
    float y2 = x2 * c - x1 * sn;
    float ss = y1 * y1 + y2 * y2;
#pragma unroll
    for (int m = 1; m < 64; m <<= 1) ss += __shfl_xor(ss, m, 64);
    float rinv = rsqrtf(ss * (1.0f / 128.0f) + eps);
    p[lane]      = __float2bfloat16(y1 * rinv);
    p[lane + 64] = __float2bfloat16(y2 * rinv);
}

// ---------------------------------------------------------------------------
// K pack: post-RoPE K (strided in qkv) -> Kp[gy][kt][row32][d] bf16.
// Per (group, key-tile) the 32x128 tile is one contiguous 8 KB chunk.
// ---------------------------------------------------------------------------
__global__ __launch_bounds__(256) void k_pack(const __hip_bfloat16* __restrict__ Kin,
                                              bf16_t* __restrict__ Kp) {
    const int idx = blockIdx.x * 256 + threadIdx.x;   // 8 bf16 per thread
    const int d0 = (idx & 15) * 8;
    const int row = (idx >> 4) & 31;
    const int kt = (idx >> 9) & 63;
    const int gy = idx >> 15;
    const int kvh = gy & 3;
    const int bb = gy >> 2;
    const bf16_t* src = (const bf16_t*)Kin + (size_t)(bb * S_ + kt * 32 + row) * 3072 + kvh * D_ + d0;
    *(uint4*)(Kp + (size_t)idx * 8) = *(const uint4*)src;
}

// ---------------------------------------------------------------------------
// V pair-pack transpose: V[s][d] (strided in qkv) -> Vp[gy][kt][d][kp] u32
// where u32 = (V[32kt+kp][d], V[32kt+16+kp][d]).  kp = quad*4 + word is the
// fragment pair order the Pb path produces.
// ---------------------------------------------------------------------------
__global__ __launch_bounds__(256) void v_pack(const __hip_bfloat16* __restrict__ V,
                                              unsigned* __restrict__ Vp, int ldv) {
    const int idx = blockIdx.x * 256 + threadIdx.x;
    const int kp = idx & 15;
    const int d  = (idx >> 4) & 127;
    const int kt = (idx >> 11) & 63;
    const int gy = idx >> 17;                 // b*HKV + kvh
    const int kvh = gy & 3;
    const int b = gy >> 2;
    const unsigned short* p = (const unsigned short*)V
        + (size_t)(b * S_ + 32 * kt + kp) * ldv + kvh * D_ + d;
    unsigned lo = p[0];
    unsigned hi = p[(size_t)16 * ldv];
    Vp[idx] = lo | (hi << 16);
}

// ---------------------------------------------------------------------------
// Flash attention v8: v7 structure with the register cap REMOVED.
//
// Launch-bounds decode (4 data points): the 2nd __launch_bounds__ arg acts as
// CUDA-style min BLOCKS per CU (default 2), not waves/EU:
//   v3 (256,2) -> cap 256 (VGPR 124);  v5 (1024,4) -> clamped 2 blocks = 8
//   waves/SIMD -> cap 64 (VGPR 64!);  v6 (512,2) -> 4 waves/SIMD -> cap 128
//   (500 MB spill);  v7 (512) -> default 2 -> cap 128 (compiler sank the
//   prefetch loads to fit -> pipeline destroyed, 132 us).
// Fix: __launch_bounds__(512, 1) -> 1 block x 8 waves = 2 waves/SIMD ->
// 256-VGPR cap.  The kernel needs ~240, so the written K-double-buffer +
// top-of-loop V-issue pipeline can finally materialize in the ISA.
// Everything else identical to v7 (single-variable change).
// ---------------------------------------------------------------------------
#define M0F 16.5f

__global__ __launch_bounds__(512, 1) void attn_flash8(const __hip_bfloat16* __restrict__ Q,
                                                      const bf16_t* __restrict__ Kp,
                                                      const unsigned* __restrict__ Vp,
                                                      __hip_bfloat16* __restrict__ O) {
    __shared__ unsigned PbS[8][2][16][16];   // 16 KB, wave-private P pair-pack

    const int tid = threadIdx.x;
    const int w = tid >> 6;
    const int lane = tid & 63;
    const int r = lane & 15;
    const int quad = lane >> 4;

    const int id = blockIdx.x;
    const int gy = id & 7;                  // group -> XCD pin
    const int u = id >> 3;
    const int hh = u & 3;
    const int i = u >> 2;                   // 0..7
    const int kvh = gy & 3;
    const int b = gy >> 2;
    const int h = kvh * 4 + hh;

    // Complementary tile table: waves w=0..3 get {i, 31-i, 16+i, 15-i};
    // waves w+4 get 63 - that.  Covers 0..63 exactly across i=0..7; SIMD
    // (w&3) hosts w and w^4 -> per-SIMD work = 65 key-tiles, exact balance.
    const int s4 = w & 3;
    int tlo = (s4 == 0) ? i : (s4 == 1) ? (31 - i) : (s4 == 2) ? (16 + i) : (15 - i);
    const int qt = (w < 4) ? tlo : (63 - tlo);
    const int q0 = qt * 32;

    const bf16_t* Kg = Kp + (size_t)gy * (64 * 32 * 128);
    const unsigned* Vg = Vp + (size_t)gy * (64 * 128 * 16);

    // Q fragments
    bf16x8 qf[2][4];
#pragma unroll
    for (int t = 0; t < 2; ++t) {
        const bf16_t* qp = (const bf16_t*)Q + (size_t)(b * S_ + q0 + t * 16 + r) * 3072 + h * D_ + quad * 8;
#pragma unroll
        for (int c = 0; c < 4; ++c) qf[t][c] = *(const bf16x8*)(qp + c * 32);
    }

    f32x4 oacc[2][8] = {};
    f32x4 lacc[2] = {};

    bf16x8 ones;
#pragma unroll
    for (int j = 0; j < 8; ++j) ones[j] = (bf16_t)1.0f;

    const float SC2 = 0.08838834764831845f * 1.4426950408889634f;  // D^-0.5 * log2(e)

    unsigned* pbw = &PbS[w][0][0][0];
    const int pwi = (((r >> 2) ^ quad) & 3) * 4 + (r & 3);   // write slot
    const int pgrp = ((quad ^ (r >> 2)) & 3) * 4;            // read group

    bf16x8 ka[8], kb[8], va[8];

#define LOADK(KB, KT) do {                                                    \
        const bf16_t* kp_ = Kg + (size_t)(KT) * 4096 + r * 128 + quad * 8;    \
        KB[0] = *(const bf16x8*)(kp_);                                        \
        KB[1] = *(const bf16x8*)(kp_ + 2048);                                 \
        KB[2] = *(const bf16x8*)(kp_ + 32);                                   \
        KB[3] = *(const bf16x8*)(kp_ + 2048 + 32);                            \
        KB[4] = *(const bf16x8*)(kp_ + 64);                                   \
        KB[5] = *(const bf16x8*)(kp_ + 2048 + 64);                            \
        KB[6] = *(const bf16x8*)(kp_ + 96);                                   \
        KB[7] = *(const bf16x8*)(kp_ + 2048 + 96);                            \
    } while (0)

#define LOADV(KT) do {                                                        \
        const unsigned* vp_ = Vg + (size_t)(KT) * 2048 + r * 16 + quad * 4;   \
        va[0] = *(const bf16x8*)(vp_);                                        \
        va[1] = *(const bf16x8*)(vp_ + 256);                                  \
        va[2] = *(const bf16x8*)(vp_ + 512);                                  \
        va[3] = *(const bf16x8*)(vp_ + 768);                                  \
        va[4] = *(const bf16x8*)(vp_ + 1024);                                 \
        va[5] = *(const bf16x8*)(vp_ + 1280);                                 \
        va[6] = *(const bf16x8*)(vp_ + 1536);                                 \
        va[7] = *(const bf16x8*)(vp_ + 1792);                                 \
    } while (0)

#define STEP(KCUR, KNXT, KT) do {                                             \
        LOADV(KT);                                                            \
        f32x4 s0_[2] = {}, s1_[2] = {};                                       \
        __builtin_amdgcn_s_setprio(1);                                        \
        _Pragma("unroll")                                                     \
        for (int c = 0; c < 4; ++c) {                                         \
            _Pragma("unroll")                                                 \
            for (int t = 0; t < 2; ++t) {                                     \
                s0_[t] = __builtin_amdgcn_mfma_f32_16x16x32_bf16(qf[t][c], KCUR[c * 2], s0_[t], 0, 0, 0);     \
                s1_[t] = __builtin_amdgcn_mfma_f32_16x16x32_bf16(qf[t][c], KCUR[c * 2 + 1], s1_[t], 0, 0, 0); \
            }                                                                 \
        }                                                                     \
        __builtin_amdgcn_s_setprio(0);                                        \
        if ((KT) < qt) LOADK(KNXT, (KT) + 1);                                 \
        if ((KT) == qt) {                                                     \
            _Pragma("unroll")                                                 \
            for (int t = 0; t < 2; ++t)                                       \
                _Pragma("unroll")                                             \
                for (int g = 0; g < 4; ++g) {                                 \
                    const int qrow_ = q0 + t * 16 + quad * 4 + g;             \
                    if ((KT) * 32 + r > qrow_)      s0_[t][g] = -1e38f;       \
                    if ((KT) * 32 + 16 + r > qrow_) s1_[t][g] = -1e38f;       \
                }                                                             \
        }                                                                     \
        _Pragma("unroll")                                                     \
        for (int t = 0; t < 2; ++t)                                           \
            _Pragma("unroll")                                                 \
            for (int g = 0; g < 4; ++g) {                                     \
                const float p0_ = exp2f(fmaf(s0_[t][g], SC2, -M0F));          \
                const float p1_ = exp2f(fmaf(s1_[t][g], SC2, -M0F));          \
                pbw[t * 256 + (quad * 4 + g) * 16 + pwi] = packbf2(p0_, p1_); \
            }                                                                 \
        bf16x8 pf0_ = *(const bf16x8*)&pbw[r * 16 + pgrp];                    \
        bf16x8 pf1_ = *(const bf16x8*)&pbw[256 + r * 16 + pgrp];              \
        lacc[0] = __builtin_amdgcn_mfma_f32_16x16x32_bf16(pf0_, ones, lacc[0], 0, 0, 0); \
        lacc[1] = __builtin_amdgcn_mfma_f32_16x16x32_bf16(pf1_, ones, lacc[1], 0, 0, 0); \
        __builtin_amdgcn_s_setprio(1);                                        \
        _Pragma("unroll")                                                     \
        for (int ns = 0; ns < 8; ++ns) {                                      \
            oacc[0][ns] = __builtin_amdgcn_mfma_f32_16x16x32_bf16(pf0_, va[ns], oacc[0][ns], 0, 0, 0); \
            oacc[1][ns] = __builtin_amdgcn_mfma_f32_16x16x32_bf16(pf1_, va[ns], oacc[1][ns], 0, 0, 0); \
        }                                                                     \
        __builtin_amdgcn_s_setprio(0);                                        \
    } while (0)

    LOADK(ka, 0);
    int kt = 0;
    for (;;) {
        STEP(ka, kb, kt);
        if (++kt > qt) break;
        STEP(kb, ka, kt);
        if (++kt > qt) break;
    }
#undef LOADK
#undef LOADV
#undef STEP

    // ---- epilogue: normalize + scalar stores (proven 16 MB WRITE) ----
#pragma unroll
    for (int t = 0; t < 2; ++t) {
#pragma unroll
        for (int g = 0; g < 4; ++g) {
            const float inv = 1.0f / lacc[t][g];
            const int qrow = q0 + t * 16 + quad * 4 + g;
            __hip_bfloat16* op = O + (size_t)(b * S_ + qrow) * 2048 + h * D_;
#pragma unroll
            for (int ns = 0; ns < 8; ++ns)
                op[ns * 16 + r] = __float2bfloat16(oacc[t][ns][g] * inv);
        }
    }
}

// ---------------------------------------------------------------------------
// Flash attention v3 (kept for the fallback path).
// ---------------------------------------------------------------------------
#define KT_ 32
#define LDK 136

__global__ __launch_bounds__(256, 2) void attn_flash3(const __hip_bfloat16* __restrict__ Q,
                                                      const __hip_bfloat16* __restrict__ K,
                                                      const __hip_bfloat16* __restrict__ V,
                                                      __hip_bfloat16* __restrict__ O,
                                                      int ldq, int ldkv, int ldo) {
    __shared__ unsigned short Ks[KT_][LDK];        // 8704 B
    __shared__ unsigned int Vt[D_ * 16];           // 8192 B (pair-packed)
    __shared__ unsigned int Pb[4][2][16][16];      // 8192 B (pair-packed)

    const int tid = threadIdx.x;
    const int w = tid >> 6;
    const int lane = tid & 63;
    const int r = lane & 15;
    const int quad = lane >> 4;

    const int gy = blockIdx.y;                     // b*HKV + kvh
    const int kvh = gy % HKV_;
    const int b = gy / HKV_;
    const int qt = b ? blockIdx.x : (gridDim.x - 1 - blockIdx.x);
    const int q0 = qt * 32;
    const int h = kvh * 4 + w;

    bf16x8 qf[2][4];
#pragma unroll
    for (int t = 0; t < 2; ++t) {
        const bf16_t* qp = (const bf16_t*)Q + (size_t)(b * S_ + q0 + t * 16 + r) * ldq + h * D_ + quad * 8;
#pragma unroll
        for (int c = 0; c < 4; ++c) qf[t][c] = *(const bf16x8*)(qp + c * 32);
    }

    f32x4 oacc[2][8] = {};
    f32x4 lacc[2] = {};
    float m_i[2][4];
#pragma unroll
    for (int t = 0; t < 2; ++t)
#pragma unroll
        for (int g = 0; g < 4; ++g) m_i[t][g] = -3e38f;

    const bf16_t* Kg = (const bf16_t*)K + (size_t)b * S_ * ldkv + kvh * D_;
    const bf16_t* Vg = (const bf16_t*)V + (size_t)b * S_ * ldkv + kvh * D_;

    bf16x8 ones;
#pragma unroll
    for (int j = 0; j < 8; ++j) ones[j] = (bf16_t)1.0f;

    const float SC2 = 0.08838834764831845f * 1.4426950408889634f;

    const int skey = tid >> 4;
    const int sdc = tid & 15;
    union U4 { uint4 u; unsigned short s[8]; };
    U4 rk0, rk1, rv0, rv1;
    {
        const size_t o0 = (size_t)skey * ldkv + sdc * 8;
        const size_t o1 = o0 + (size_t)16 * ldkv;
        rk0.u = *(const uint4*)(Kg + o0);
        rk1.u = *(const uint4*)(Kg + o1);
        rv0.u = *(const uint4*)(Vg + o0);
        rv1.u = *(const uint4*)(Vg + o1);
    }

    for (int kt = 0; kt <= qt; ++kt) {
        const int k0 = kt * KT_;
        __syncthreads();
        *(uint4*)&Ks[skey][sdc * 8] = rk0.u;
        *(uint4*)&Ks[skey + 16][sdc * 8] = rk1.u;
#pragma unroll
        for (int j = 0; j < 8; ++j) {
            const int d = sdc * 8 + j;
            const int f = ((j >> 1) & 3) ^ (sdc & 3);
            const int grp = (skey >> 2) ^ f;
            Vt[d * 16 + grp * 4 + (skey & 3)] = (unsigned)rv0.s[j] | ((unsigned)rv1.s[j] << 16);
        }
        __syncthreads();
        if (kt < qt) {
            const size_t o0 = (size_t)(k0 + KT_ + skey) * ldkv + sdc * 8;
            const size_t o1 = o0 + (size_t)16 * ldkv;
            rk0.u = *(const uint4*)(Kg + o0);
            rk1.u = *(const uint4*)(Kg + o1);
            rv0.u = *(const uint4*)(Vg + o0);
            rv1.u = *(const uint4*)(Vg + o1);
        }

        f32x4 s0[2] = {}, s1[2] = {};
#pragma unroll
        for (int c = 0; c < 4; ++c) {
            bf16x8 kb0 = *(const bf16x8*)&Ks[r][c * 32 + quad * 8];
            bf16x8 kb1 = *(const bf16x8*)&Ks[16 + r][c * 32 + quad * 8];
#pragma unroll
            for (int t = 0; t < 2; ++t) {
                s0[t] = __builtin_amdgcn_mfma_f32_16x16x32_bf16(qf[t][c], kb0, s0[t], 0, 0, 0);
                s1[t] = __builtin_amdgcn_mfma_f32_16x16x32_bf16(qf[t][c], kb1, s1[t], 0, 0, 0);
            }
        }

        const bool bnd = (kt == qt);
#pragma unroll
        for (int t = 0; t < 2; ++t) {
            float mt[4];
#pragma unroll
            for (int g = 0; g < 4; ++g) {
                s0[t][g] *= SC2;
                s1[t][g] *= SC2;
                if (bnd) {
                    const int qrow = q0 + t * 16 + quad * 4 + g;
                    if (k0 + r > qrow)      s0[t][g] = -1e38f;
                    if (k0 + 16 + r > qrow) s1[t][g] = -1e38f;
                }
                mt[g] = fmaxf(s0[t][g], s1[t][g]);
            }
#pragma unroll
            for (int msk = 1; msk < 16; msk <<= 1) {
#pragma unroll
                for (int g = 0; g < 4; ++g) mt[g] = fmaxf(mt[g], __shfl_xor(mt[g], msk, 64));
            }
            bool upd = false;
#pragma unroll
            for (int g = 0; g < 4; ++g) upd |= (mt[g] > m_i[t][g]);
            if (__ballot(upd)) {
#pragma unroll
                for (int g = 0; g < 4; ++g) {
                    const float mn = fmaxf(m_i[t][g], mt[g]);
                    const float al = exp2f(m_i[t][g] - mn);
                    m_i[t][g] = mn;
                    lacc[t][g] *= al;
#pragma unroll
                    for (int ns = 0; ns < 8; ++ns) oacc[t][ns][g] *= al;
                }
            }
#pragma unroll
            for (int g = 0; g < 4; ++g) {
                const float p0 = exp2f(s0[t][g] - m_i[t][g]);
                const float p1 = exp2f(s1[t][g] - m_i[t][g]);
                const int row = quad * 4 + g;
                Pb[w][t][row][(((r >> 2) ^ quad) & 3) * 4 + (r & 3)] = packbf2(p0, p1);
            }
        }

        const int pgrp = ((quad ^ (r >> 2)) & 3) * 4;
        bf16x8 pf0 = *(const bf16x8*)&Pb[w][0][r][pgrp];
        bf16x8 pf1 = *(const bf16x8*)&Pb[w][1][r][pgrp];

        lacc[0] = __builtin_amdgcn_mfma_f32_16x16x32_bf16(pf0, ones, lacc[0], 0, 0, 0);
        lacc[1] = __builtin_amdgcn_mfma_f32_16x16x32_bf16(pf1, ones, lacc[1], 0, 0, 0);

#pragma unroll
        for (int ns = 0; ns < 8; ++ns) {
            const int d = ns * 16 + r;
            const int f = ((r >> 1) & 3) ^ ((2 * ns + (r >> 3)) & 3);
            bf16x8 vf = *(const bf16x8*)&Vt[d * 16 + ((quad ^ f) & 3) * 4];
            oacc[0][ns] = __builtin_amdgcn_mfma_f32_16x16x32_bf16(pf0, vf, oacc[0][ns], 0, 0, 0);
            oacc[1][ns] = __builtin_amdgcn_mfma_f32_16x16x32_bf16(pf1, vf, oacc[1][ns], 0, 0, 0);
        }
    }

#pragma unroll
    for (int t = 0; t < 2; ++t) {
#pragma unroll
        for (int g = 0; g < 4; ++g) {
            const float inv = 1.0f / lacc[t][g];
            const int qrow = q0 + t * 16 + quad * 4 + g;
            __hip_bfloat16* op = O + (size_t)(b * S_ + qrow) * ldo + h * D_;
#pragma unroll
            for (int ns = 0; ns < 8; ++ns)
                op[ns * 16 + r] = __float2bfloat16(oacc[t][ns][g] * inv);
        }
    }
}

// ---------------------------------------------------------------------------
extern "C" void kernel_launch(void* const* d_in, const int* in_sizes, int n_in,
                              void* d_out, int out_size, void* d_ws, size_t ws_size,
                              hipStream_t stream) {
    const void* x    = d_in[0];
    const void* cosp = d_in[1];
    const void* sinp = d_in[2];
    const void* Wq   = d_in[3];
    const void* Wk   = d_in[4];
    const void* Wv   = d_in[5];
    const void* Wo   = d_in[6];

    const int M = B_ * S_;                 // 4096
    const size_t MB = 1ull << 20;

    if (ws_size >= 28 * MB + 64) {
        // Fast path. ws: [0,16M)=xb then ao; [16M,28M)=Wqkv, then Wo at [16M,24M)
        // and packed-V at [24M,28M); flag at 28M.
        // d_out: qkv bf16 [4096,3072] (24 MB), packed-K at [24M,28M), then output.
        char* ws = (char*)d_ws;
        bf16_t* xb = (bf16_t*)ws;
        bf16_t* wb = (bf16_t*)(ws + 16 * MB);
        bf16_t* wo = (bf16_t*)(ws + 16 * MB);
        unsigned* vp4 = (unsigned*)(ws + 24 * MB);
        bf16_t* ao = (bf16_t*)ws;
        int* flag  = (int*)(ws + 28 * MB);
        bf16_t* qkv = (bf16_t*)d_out;
        bf16_t* kp8 = (bf16_t*)((char*)d_out + 24 * MB);

        detect_dtype<<<1, 64, 0, stream>>>((const unsigned*)x, flag);

        // convert x, Wq, Wk, Wv -> bf16 (Wqkv contiguous [3072, 2048])
        Cseg sx{x,  xb,                          (B_ * S_ * HID_) / 8};
        Cseg sq{Wq, wb,                          (H_ * D_ * HID_) / 8};
        Cseg sk{Wk, wb + (size_t)2048 * HID_,    (HKV_ * D_ * HID_) / 8};
        Cseg sv{Wv, wb + (size_t)2560 * HID_,    (HKV_ * D_ * HID_) / 8};
        convert_bf16<<<dim3(4096, 4), 256, 0, stream>>>(sx, sq, sk, sv, flag);

        // Fused QKV projection: [4096,2048] x [3072,2048]^T -> qkv [4096,3072]
        gemm_lds<<<dim3(3072 / 128, M / 128), 256, 0, stream>>>(xb, wb, qkv, M, 3072, HID_, flag, 0);

        // convert Wo -> bf16 (wb dead; wo overlays wb)
        Cseg so{Wo, wo, (HID_ * H_ * D_) / 8};
        convert_bf16<<<dim3(2048, 1), 256, 0, stream>>>(so, so, so, so, flag);

        // pack V (no RoPE on V): qkv cols [2560,3072) -> vp4
        v_pack<<<(B_ * HKV_ * D_ * 64 * 16) / 256, 256, 0, stream>>>(
            (const __hip_bfloat16*)(qkv + 2560), vp4, 3072);

        // RoPE + RMSNorm in-place: q cols [0,2048), k cols [2048,2560)
        rope_rms<<<(B_ * S_ * H_) / 4, 256, 0, stream>>>((__hip_bfloat16*)qkv, cosp, sinp, H_, 3072, flag);
        rope_rms<<<(B_ * S_ * HKV_) / 4, 256, 0, stream>>>((__hip_bfloat16*)(qkv + 2048), cosp, sinp, HKV_, 3072, flag);

        // pack post-RoPE K into per-tile-contiguous layout
        k_pack<<<dim3(1024), 256, 0, stream>>>((const __hip_bfloat16*)(qkv + 2048), kp8);

        // Flash attention v8: Q strided in qkv, K/V packed; O -> ao (xb dead)
        attn_flash8<<<dim3(256), 512, 0, stream>>>(
            (const __hip_bfloat16*)qkv, kp8, vp4, (__hip_bfloat16*)ao);

        // Output projection: ao x Wo^T -> d_out (fp32 if flag=0)
        gemm_lds<<<dim3(HID_ / 128, M / 128), 256, 0, stream>>>(ao, wo, d_out, M, HID_, H_ * D_, flag, 1);
    } else {
        // Fallback: proven path (ws >= 16 MB + 4).
        __hip_bfloat16* qb = (__hip_bfloat16*)d_ws;
        int* flag = (int*)((char*)d_ws + (size_t)M * (H_ * D_) * sizeof(__hip_bfloat16));
        __hip_bfloat16* kb = (__hip_bfloat16*)d_out;
        __hip_bfloat16* vb = kb + (size_t)M * (HKV_ * D_);

        detect_dtype<<<1, 64, 0, stream>>>((const unsigned*)x, flag);

        gemm_bt<<<dim3((H_ * D_) / 64, M / 64), 256, 0, stream>>>(x, Wq, qb, M, H_ * D_, HID_, flag, 0);
        gemm_bt<<<dim3((HKV_ * D_) / 64, M / 64), 256, 0, stream>>>(x, Wk, kb, M, HKV_ * D_, HID_, flag, 0);
        gemm_bt<<<dim3((HKV_ * D_) / 64, M / 64), 256, 0, stream>>>(x, Wv, vb, M, HKV_ * D_, HID_, flag, 0);

        rope_rms<<<(B_ * S_ * H_) / 4, 256, 0, stream>>>(qb, cosp, sinp, H_, H_ * D_, flag);
        rope_rms<<<(B_ * S_ * HKV_) / 4, 256, 0, stream>>>(kb, cosp, sinp, HKV_, HKV_ * D_, flag);

        attn_flash3<<<dim3(S_ / 32, B_ * HKV_), 256, 0, stream>>>(qb, kb, vb, qb, H_ * D_, HKV_ * D_, H_ * D_);

        gemm_bt<<<dim3(HID_ / 64, M / 64), 256, 0, stream>>>(qb, Wo, d_out, M, HID_, H_ * D_, flag, 1);
    }
}

// Round 7
// 349.314 us; speedup vs baseline: 1.5459x; 1.1454x over previous
//
#include <hip/hip_runtime.h>
#include <hip/hip_bf16.h>

// Problem constants
#define B_  2
#define S_  2048
#define HID_ 2048
#define H_  16
#define HKV_ 4
#define D_  128

typedef __bf16 bf16_t;
typedef bf16_t bf16x8 __attribute__((ext_vector_type(8)));
typedef float f32x4 __attribute__((ext_vector_type(4)));

typedef __attribute__((address_space(3))) unsigned int lds_u32_t;
typedef const __attribute__((address_space(1))) unsigned int glob_u32_t;

// async global->LDS, 16 B per lane; LDS dest = wave-uniform base + lane*16
__device__ __forceinline__ void gl2lds16(const bf16_t* g, bf16_t* l) {
    __builtin_amdgcn_global_load_lds((glob_u32_t*)g, (lds_u32_t*)l, 16, 0, 0);
}

__device__ __forceinline__ unsigned packbf2(float a, float b) {
    union { bf16_t h[2]; unsigned u; } p;
    p.h[0] = (bf16_t)a;
    p.h[1] = (bf16_t)b;
    return p.u;
}

// ---------------------------------------------------------------------------
// Runtime dtype detection: flag=1 if inputs are bf16, 0 if fp32.
// ---------------------------------------------------------------------------
__global__ void detect_dtype(const unsigned* __restrict__ x, int* __restrict__ flag) {
    int lane = threadIdx.x;
    int c = 0;
#pragma unroll
    for (int i = 0; i < 16; ++i) {
        unsigned w = x[lane * 16 + i];
        unsigned e = (w >> 7) & 0xFF;
        c += (e >= 117 && e <= 137) ? 1 : 0;
    }
#pragma unroll
    for (int m = 1; m < 64; m <<= 1) c += __shfl_xor(c, m, 64);
    if (lane == 0) *flag = (c >= 512) ? 1 : 0;
}

// ---------------------------------------------------------------------------
// Conversion pass: src (fp32 or bf16 per flag) -> bf16 dst. 8 elems/thread.
// ---------------------------------------------------------------------------
struct Cseg { const void* src; bf16_t* dst; int n8; };

__global__ __launch_bounds__(256) void convert_bf16(Cseg s0, Cseg s1, Cseg s2, Cseg s3,
                                                    const int* __restrict__ flagp) {
    Cseg s = (blockIdx.y == 0) ? s0 : (blockIdx.y == 1) ? s1 : (blockIdx.y == 2) ? s2 : s3;
    const int i = blockIdx.x * 256 + threadIdx.x;
    if (i >= s.n8) return;
    if (*flagp) {
        ((uint4*)s.dst)[i] = ((const uint4*)s.src)[i];
    } else {
        const float4* p = (const float4*)s.src + (size_t)i * 2;
        float4 u = p[0], v = p[1];
        bf16x8 r;
        r[0] = (bf16_t)u.x; r[1] = (bf16_t)u.y; r[2] = (bf16_t)u.z; r[3] = (bf16_t)u.w;
        r[4] = (bf16_t)v.x; r[5] = (bf16_t)v.y; r[6] = (bf16_t)v.z; r[7] = (bf16_t)v.w;
        *(bf16x8*)(s.dst + (size_t)i * 8) = r;
    }
}

// ---------------------------------------------------------------------------
// m97-structure GEMM: C[m,n] = sum_k A[m,k]*W[n,k], A/W bf16 row-major.
// 128x128 tile, BK=32, LDS staging via global_load_lds width=16.
// ---------------------------------------------------------------------------
__global__ __launch_bounds__(256) void gemm_lds(const bf16_t* __restrict__ A,
                                                const bf16_t* __restrict__ W,
                                                void* __restrict__ C,
                                                int M, int N, int K,
                                                const int* __restrict__ flagp, int osel) {
    __shared__ bf16_t As[128 * 32];
    __shared__ bf16_t Bs[128 * 32];

    const int tid = threadIdx.x;
    const int w = tid >> 6;
    const int lane = tid & 63;
    const int r = lane & 15;
    const int quad = lane >> 4;
    const int m0 = blockIdx.y * 128;
    const int n0 = blockIdx.x * 128;
    const bool of32 = osel && (*flagp == 0);

    const int mh = (w & 1) * 64;
    const int nh = (w >> 1) * 64;

    const int c0 = w * 2;
    const int srow = lane >> 2;
    const int scol = (lane & 3) * 8;
    const bf16_t* Ag0 = A + (size_t)(m0 + c0 * 16 + srow) * K + scol;
    const bf16_t* Ag1 = A + (size_t)(m0 + c0 * 16 + 16 + srow) * K + scol;
    const bf16_t* Wg0 = W + (size_t)(n0 + c0 * 16 + srow) * K + scol;
    const bf16_t* Wg1 = W + (size_t)(n0 + c0 * 16 + 16 + srow) * K + scol;
    bf16_t* Al0 = As + c0 * 512;
    bf16_t* Al1 = As + (c0 + 1) * 512;
    bf16_t* Bl0 = Bs + c0 * 512;
    bf16_t* Bl1 = Bs + (c0 + 1) * 512;

    f32x4 acc[4][4] = {};

    for (int k0 = 0; k0 < K; k0 += 32) {
        __syncthreads();
        gl2lds16(Ag0 + k0, Al0);
        gl2lds16(Ag1 + k0, Al1);
        gl2lds16(Wg0 + k0, Bl0);
        gl2lds16(Wg1 + k0, Bl1);
        __syncthreads();

        bf16x8 a[4], b[4];
#pragma unroll
        for (int mi = 0; mi < 4; ++mi)
            a[mi] = *(const bf16x8*)&As[(mh + mi * 16 + r) * 32 + quad * 8];
#pragma unroll
        for (int ni = 0; ni < 4; ++ni)
            b[ni] = *(const bf16x8*)&Bs[(nh + ni * 16 + r) * 32 + quad * 8];
#pragma unroll
        for (int mi = 0; mi < 4; ++mi)
#pragma unroll
            for (int ni = 0; ni < 4; ++ni)
                acc[mi][ni] = __builtin_amdgcn_mfma_f32_16x16x32_bf16(a[mi], b[ni], acc[mi][ni], 0, 0, 0);
    }

#pragma unroll
    for (int mi = 0; mi < 4; ++mi) {
#pragma unroll
        for (int ni = 0; ni < 4; ++ni) {
#pragma unroll
            for (int g = 0; g < 4; ++g) {
                const int row = m0 + mh + mi * 16 + quad * 4 + g;
                const int col = n0 + nh + ni * 16 + r;
                if (of32) ((float*)C)[(size_t)row * N + col] = acc[mi][ni][g];
                else ((__hip_bfloat16*)C)[(size_t)row * N + col] = __float2bfloat16(acc[mi][ni][g]);
            }
        }
    }
}

// ---------------------------------------------------------------------------
// Fallback direct-from-global GEMM (proven path).
// ---------------------------------------------------------------------------
template <bool F32>
__device__ __forceinline__ bf16x8 load8(const void* base, size_t off) {
    bf16x8 r;
    if constexpr (F32) {
        const float4* p = (const float4*)((const float*)base + off);
        float4 u = p[0], v = p[1];
        r[0] = (bf16_t)u.x; r[1] = (bf16_t)u.y; r[2] = (bf16_t)u.z; r[3] = (bf16_t)u.w;
        r[4] = (bf16_t)v.x; r[5] = (bf16_t)v.y; r[6] = (bf16_t)v.z; r[7] = (bf16_t)v.w;
    } else {
        r = *(const bf16x8*)((const bf16_t*)base + off);
    }
    return r;
}

template <bool AF32, bool WF32, bool OF32>
__device__ __forceinline__ void gemm_body(const void* __restrict__ A, const void* __restrict__ W,
                                          void* __restrict__ C, int M, int N, int K) {
    const int wave = threadIdx.x >> 6;
    const int lane = threadIdx.x & 63;
    const int r = lane & 15;
    const int quad = lane >> 4;
    const int m0 = blockIdx.y * 64 + wave * 16;
    const int n0 = blockIdx.x * 64;

    f32x4 acc[4] = {};
    const size_t aoff = (size_t)(m0 + r) * K + quad * 8;
    const size_t woff = (size_t)(n0 + r) * K + quad * 8;

    for (int k0 = 0; k0 < K; k0 += 32) {
        bf16x8 a = load8<AF32>(A, aoff + k0);
#pragma unroll
        for (int ns = 0; ns < 4; ++ns) {
            bf16x8 b = load8<WF32>(W, woff + (size_t)(ns * 16) * K + k0);
            acc[ns] = __builtin_amdgcn_mfma_f32_16x16x32_bf16(a, b, acc[ns], 0, 0, 0);
        }
    }

#pragma unroll
    for (int ns = 0; ns < 4; ++ns) {
#pragma unroll
        for (int reg = 0; reg < 4; ++reg) {
            int m = m0 + quad * 4 + reg;
            int n = n0 + ns * 16 + r;
            if constexpr (OF32) ((float*)C)[(size_t)m * N + n] = acc[ns][reg];
            else ((__hip_bfloat16*)C)[(size_t)m * N + n] = __float2bfloat16(acc[ns][reg]);
        }
    }
}

__global__ __launch_bounds__(256) void gemm_bt(const void* __restrict__ A, const void* __restrict__ W,
                                               void* __restrict__ C, int M, int N, int K,
                                               const int* __restrict__ flagp, int mode) {
    const int bf = *flagp;
    if (bf) {
        gemm_body<false, false, false>(A, W, C, M, N, K);
    } else if (mode == 0) {
        gemm_body<true, true, false>(A, W, C, M, N, K);
    } else {
        gemm_body<false, true, true>(A, W, C, M, N, K);
    }
}

// ---------------------------------------------------------------------------
// In-place RoPE + RMSNorm on bf16 rows. Row (bs,h) at base + bs*ld + h*D.
// ---------------------------------------------------------------------------
__global__ __launch_bounds__(256) void rope_rms(__hip_bfloat16* __restrict__ qk,
                                                const void* __restrict__ cosp,
                                                const void* __restrict__ sinp,
                                                int NH, int ld, const int* __restrict__ flagp) {
    const int bf = *flagp;
    const int wave = threadIdx.x >> 6;
    const int lane = threadIdx.x & 63;
    const int row = blockIdx.x * 4 + wave;   // row = bs*NH + h
    const int h = row % NH;
    const int bs = row / NH;
    const int s = bs % S_;

    __hip_bfloat16* p = qk + (size_t)bs * ld + h * D_;
    float x1 = __bfloat162float(p[lane]);
    float x2 = __bfloat162float(p[lane + 64]);
    float c, sn, eps;
    if (bf) {
        c   = __bfloat162float(((const __hip_bfloat16*)cosp)[s * 64 + lane]);
        sn  = __bfloat162float(((const __hip_bfloat16*)sinp)[s * 64 + lane]);
        eps = 0.0078125f;
    } else {
        c   = ((const float*)cosp)[s * 64 + lane];
        sn  = ((const float*)sinp)[s * 64 + lane];
        eps = 1.1920929e-07f;
    }
    float y1 = x1 * c + x2 * sn;
    float y2 = x2 * c - x1 * sn;
    float ss = y1 * y1 + y2 * y2;
#pragma unroll
    for (int m = 1; m < 64; m <<= 1) ss += __shfl_xor(ss, m, 64);
    float rinv = rsqrtf(ss * (1.0f / 128.0f) + eps);
    p[lane]      = __float2bfloat16(y1 * rinv);
    p[lane + 64] = __float2bfloat16(y2 * rinv);
}

// ---------------------------------------------------------------------------
// K pack: post-RoPE K (strided in qkv) -> Kp, per (gy,kt) an 8 KB tile laid
// out EXACTLY as the attention wants it in LDS, with the bank-swizzle baked
// in (rule: linear gl2lds dest + swizzled SOURCE + swizzled read):
//   tile byte layout: row r (0..31) at r*256; 16 B slot sl at sl*16 where
//   sl = slot ^ (r & 15), slot = d0/8.  Turns the 16-way ds_read_b128
//   conflict of row-major [32][128] into a free 2-way.
// Writes perfectly linear (thread idx == dst chunk); reads strided from qkv.
// ---------------------------------------------------------------------------
__global__ __launch_bounds__(256) void k_pack(const __hip_bfloat16* __restrict__ Kin,
                                              bf16_t* __restrict__ Kp) {
    const int idx = blockIdx.x * 256 + threadIdx.x;   // one 16 B chunk
    const int sl = idx & 15;                          // swizzled slot
    const int row = (idx >> 4) & 31;
    const int kt = (idx >> 9) & 63;
    const int gy = idx >> 15;
    const int slot = sl ^ (row & 15);                 // logical slot -> d0 = slot*8
    const int kvh = gy & 3;
    const int bb = gy >> 2;
    const bf16_t* src = (const bf16_t*)Kin + (size_t)(bb * S_ + kt * 32 + row) * 3072 + kvh * D_ + slot * 8;
    *(uint4*)(Kp + (size_t)idx * 8) = *(const uint4*)src;
}

// ---------------------------------------------------------------------------
// V pair-pack transpose: per (gy,kt) an 8 KB tile of u32 pairs
// (V[32kt+kp][d], V[32kt+16+kp][d]) laid out for conflict-free swizzled
// LDS reads: u32 index = d*16 + sl*4 + (kp&3), sl = (kp>>2) ^ ((d>>1)&3).
// Fragment contents identical to the proven v3..v8 Pb/PV algebra.
// ---------------------------------------------------------------------------
__global__ __launch_bounds__(256) void v_pack(const __hip_bfloat16* __restrict__ V,
                                              unsigned* __restrict__ Vp, int ldv) {
    const int idx = blockIdx.x * 256 + threadIdx.x;   // one u32
    const int j  = idx & 3;                           // kp & 3
    const int sl = (idx >> 2) & 3;                    // swizzled slot
    const int d  = (idx >> 4) & 127;
    const int kt = (idx >> 11) & 63;
    const int gy = idx >> 17;                         // b*HKV + kvh
    const int s  = sl ^ ((d >> 1) & 3);               // logical slot
    const int kp = s * 4 + j;
    const int kvh = gy & 3;
    const int b = gy >> 2;
    const unsigned short* p = (const unsigned short*)V
        + (size_t)(b * S_ + 32 * kt + kp) * ldv + kvh * D_ + d;
    unsigned lo = p[0];
    unsigned hi = p[(size_t)16 * ldv];
    Vp[idx] = lo | (hi << 16);
}

// ---------------------------------------------------------------------------
// Flash attention v9: wave-private async LDS staging, zero barriers.
//
// v7/v8 post-mortem: hipcc's scheduler SINKS register prefetch loads to
// their use sites to hold 128 VGPR (3 rounds of evidence) -> 16 serial L2
// hits/iter ~= 4900 cyc/iter.  Fighting the allocator is a dead end.
// Fix: global_load_lds staging (async, ZERO VGPRs -> cannot be sunk).
// Each wave stages its K tile (8 KB) + V tile (8 KB) into wave-private LDS
// with 16 async ops; ONE vmcnt wait per tile amortizes L2 latency 16x.
// Cross-iter overlap: frag ds_reads -> lgkmcnt(0)+sched_barrier (rule #18)
// -> issue tile kt+1 gl2lds (safe overwrite) -> softmax+MFMA hide them.
// LDS 144 KB: K 8x8KB + V 8x8KB + Pb 16KB.  1 block/CU, 2 waves/SIMD,
// NO __syncthreads anywhere (per-wave vmcnt only).
// K/V LDS reads conflict-free via the pack-time swizzle (2-way = free).
// Kept: complementary tile table, fixed-max softmax, Pb algebra, setprio,
// XCD pin, scalar O epilogue.
// ---------------------------------------------------------------------------
#define M0F 16.5f

__global__ __launch_bounds__(512, 1) void attn_flash9(const __hip_bfloat16* __restrict__ Q,
                                                      const bf16_t* __restrict__ Kp,
                                                      const unsigned* __restrict__ Vp,
                                                      __hip_bfloat16* __restrict__ O) {
    __shared__ bf16_t   Kl[8][4096];         // 64 KB, per-wave K tile (swizzled)
    __shared__ unsigned Vl[8][2048];         // 64 KB, per-wave V tile (swizzled)
    __shared__ unsigned PbS[8][2][16][16];   // 16 KB, wave-private P pair-pack

    const int tid = threadIdx.x;
    const int w = tid >> 6;
    const int lane = tid & 63;
    const int r = lane & 15;
    const int quad = lane >> 4;

    const int id = blockIdx.x;
    const int gy = id & 7;                  // group -> XCD pin
    const int u = id >> 3;
    const int hh = u & 3;
    const int i = u >> 2;                   // 0..7
    const int kvh = gy & 3;
    const int b = gy >> 2;
    const int h = kvh * 4 + hh;

    // Complementary tile table: waves w=0..3 get {i, 31-i, 16+i, 15-i};
    // waves w+4 get 63 - that.  Covers 0..63 across i=0..7.
    const int s4 = w & 3;
    int tlo = (s4 == 0) ? i : (s4 == 1) ? (31 - i) : (s4 == 2) ? (16 + i) : (15 - i);
    const int qt = (w < 4) ? tlo : (63 - tlo);
    const int q0 = qt * 32;

    const bf16_t* Ksrc = Kp + (size_t)gy * (64 * 4096);
    const unsigned* Vsrc = Vp + (size_t)gy * (64 * 2048);
    bf16_t* klds = &Kl[w][0];
    unsigned* vlds = &Vl[w][0];

    // Q fragments
    bf16x8 qf[2][4];
#pragma unroll
    for (int t = 0; t < 2; ++t) {
        const bf16_t* qp = (const bf16_t*)Q + (size_t)(b * S_ + q0 + t * 16 + r) * 3072 + h * D_ + quad * 8;
#pragma unroll
        for (int c = 0; c < 4; ++c) qf[t][c] = *(const bf16x8*)(qp + c * 32);
    }

    f32x4 oacc[2][8] = {};
    f32x4 lacc[2] = {};

    bf16x8 ones;
#pragma unroll
    for (int j = 0; j < 8; ++j) ones[j] = (bf16_t)1.0f;

    const float SC2 = 0.08838834764831845f * 1.4426950408889634f;  // D^-0.5 * log2(e)

    unsigned* pbw = &PbS[w][0][0][0];
    const int pwi = (((r >> 2) ^ quad) & 3) * 4 + (r & 3);   // Pb write slot
    const int pgrp = ((quad ^ (r >> 2)) & 3) * 4;            // Pb read group
    const int vsw = (quad ^ ((r >> 1) & 3)) * 4;             // V read sub-slot

    // 16 async 1 KB copies per tile: K 8 + V 8; zero VGPR cost.
#define ISSUE(KT) do {                                                        \
        const bf16_t* ks_ = Ksrc + (size_t)(KT) * 4096 + lane * 8;            \
        const bf16_t* vs_ = (const bf16_t*)(Vsrc + (size_t)(KT) * 2048) + lane * 8; \
        _Pragma("unroll")                                                     \
        for (int jj = 0; jj < 8; ++jj) {                                      \
            gl2lds16(ks_ + jj * 512, klds + jj * 512);                        \
            gl2lds16(vs_ + jj * 512, (bf16_t*)vlds + jj * 512);               \
        }                                                                     \
    } while (0)

    ISSUE(0);
    for (int kt = 0; kt <= qt; ++kt) {
        asm volatile("s_waitcnt vmcnt(0)" ::: "memory");   // tile kt landed

        // ---- read all frags to regs (forced live by the barrier below) ----
        bf16x8 kf[8], vf[8];
#pragma unroll
        for (int c = 0; c < 4; ++c) {
            const int sA = ((quad + 4 * c) ^ r) * 8;
            kf[2 * c]     = *(const bf16x8*)&klds[r * 128 + sA];
            kf[2 * c + 1] = *(const bf16x8*)&klds[(16 + r) * 128 + sA];
        }
#pragma unroll
        for (int ns = 0; ns < 8; ++ns)
            vf[ns] = *(const bf16x8*)&vlds[(ns * 16 + r) * 16 + vsw];

        asm volatile("s_waitcnt lgkmcnt(0)" ::: "memory");
        __builtin_amdgcn_sched_barrier(0);
        if (kt < qt) ISSUE(kt + 1);        // async; hides under compute below

        // ---- QK^T ----
        f32x4 s0_[2] = {}, s1_[2] = {};
        __builtin_amdgcn_s_setprio(1);
#pragma unroll
        for (int c = 0; c < 4; ++c) {
#pragma unroll
            for (int t = 0; t < 2; ++t) {
                s0_[t] = __builtin_amdgcn_mfma_f32_16x16x32_bf16(qf[t][c], kf[2 * c], s0_[t], 0, 0, 0);
                s1_[t] = __builtin_amdgcn_mfma_f32_16x16x32_bf16(qf[t][c], kf[2 * c + 1], s1_[t], 0, 0, 0);
            }
        }
        __builtin_amdgcn_s_setprio(0);

        if (kt == qt) {                    // diagonal mask
#pragma unroll
            for (int t = 0; t < 2; ++t)
#pragma unroll
                for (int g = 0; g < 4; ++g) {
                    const int qrow = q0 + t * 16 + quad * 4 + g;
                    if (kt * 32 + r > qrow)      s0_[t][g] = -1e38f;
                    if (kt * 32 + 16 + r > qrow) s1_[t][g] = -1e38f;
                }
        }

        // fixed-max softmax: p = 2^(s*SC2 - M0)
#pragma unroll
        for (int t = 0; t < 2; ++t)
#pragma unroll
            for (int g = 0; g < 4; ++g) {
                const float p0 = exp2f(fmaf(s0_[t][g], SC2, -M0F));
                const float p1 = exp2f(fmaf(s1_[t][g], SC2, -M0F));
                pbw[t * 256 + (quad * 4 + g) * 16 + pwi] = packbf2(p0, p1);
            }

        bf16x8 pf0 = *(const bf16x8*)&pbw[r * 16 + pgrp];
        bf16x8 pf1 = *(const bf16x8*)&pbw[256 + r * 16 + pgrp];

        lacc[0] = __builtin_amdgcn_mfma_f32_16x16x32_bf16(pf0, ones, lacc[0], 0, 0, 0);
        lacc[1] = __builtin_amdgcn_mfma_f32_16x16x32_bf16(pf1, ones, lacc[1], 0, 0, 0);

        __builtin_amdgcn_s_setprio(1);
#pragma unroll
        for (int ns = 0; ns < 8; ++ns) {
            oacc[0][ns] = __builtin_amdgcn_mfma_f32_16x16x32_bf16(pf0, vf[ns], oacc[0][ns], 0, 0, 0);
            oacc[1][ns] = __builtin_amdgcn_mfma_f32_16x16x32_bf16(pf1, vf[ns], oacc[1][ns], 0, 0, 0);
        }
        __builtin_amdgcn_s_setprio(0);
    }
#undef ISSUE

    // ---- epilogue: normalize + scalar stores (proven 16 MB WRITE) ----
#pragma unroll
    for (int t = 0; t < 2; ++t) {
#pragma unroll
        for (int g = 0; g < 4; ++g) {
            const float inv = 1.0f / lacc[t][g];
            const int qrow = q0 + t * 16 + quad * 4 + g;
            __hip_bfloat16* op = O + (size_t)(b * S_ + qrow) * 2048 + h * D_;
#pragma unroll
            for (int ns = 0; ns < 8; ++ns)
                op[ns * 16 + r] = __float2bfloat16(oacc[t][ns][g] * inv);
        }
    }
}

// ---------------------------------------------------------------------------
// Flash attention v3 (kept for the fallback path).
// ---------------------------------------------------------------------------
#define KT_ 32
#define LDK 136

__global__ __launch_bounds__(256, 2) void attn_flash3(const __hip_bfloat16* __restrict__ Q,
                                                      const __hip_bfloat16* __restrict__ K,
                                                      const __hip_bfloat16* __restrict__ V,
                                                      __hip_bfloat16* __restrict__ O,
                                                      int ldq, int ldkv, int ldo) {
    __shared__ unsigned short Ks[KT_][LDK];        // 8704 B
    __shared__ unsigned int Vt[D_ * 16];           // 8192 B (pair-packed)
    __shared__ unsigned int Pb[4][2][16][16];      // 8192 B (pair-packed)

    const int tid = threadIdx.x;
    const int w = tid >> 6;
    const int lane = tid & 63;
    const int r = lane & 15;
    const int quad = lane >> 4;

    const int gy = blockIdx.y;                     // b*HKV + kvh
    const int kvh = gy % HKV_;
    const int b = gy / HKV_;
    const int qt = b ? blockIdx.x : (gridDim.x - 1 - blockIdx.x);
    const int q0 = qt * 32;
    const int h = kvh * 4 + w;

    bf16x8 qf[2][4];
#pragma unroll
    for (int t = 0; t < 2; ++t) {
        const bf16_t* qp = (const bf16_t*)Q + (size_t)(b * S_ + q0 + t * 16 + r) * ldq + h * D_ + quad * 8;
#pragma unroll
        for (int c = 0; c < 4; ++c) qf[t][c] = *(const bf16x8*)(qp + c * 32);
    }

    f32x4 oacc[2][8] = {};
    f32x4 lacc[2] = {};
    float m_i[2][4];
#pragma unroll
    for (int t = 0; t < 2; ++t)
#pragma unroll
        for (int g = 0; g < 4; ++g) m_i[t][g] = -3e38f;

    const bf16_t* Kg = (const bf16_t*)K + (size_t)b * S_ * ldkv + kvh * D_;
    const bf16_t* Vg = (const bf16_t*)V + (size_t)b * S_ * ldkv + kvh * D_;

    bf16x8 ones;
#pragma unroll
    for (int j = 0; j < 8; ++j) ones[j] = (bf16_t)1.0f;

    const float SC2 = 0.08838834764831845f * 1.4426950408889634f;

    const int skey = tid >> 4;
    const int sdc = tid & 15;
    union U4 { uint4 u; unsigned short s[8]; };
    U4 rk0, rk1, rv0, rv1;
    {
        const size_t o0 = (size_t)skey * ldkv + sdc * 8;
        const size_t o1 = o0 + (size_t)16 * ldkv;
        rk0.u = *(const uint4*)(Kg + o0);
        rk1.u = *(const uint4*)(Kg + o1);
        rv0.u = *(const uint4*)(Vg + o0);
        rv1.u = *(const uint4*)(Vg + o1);
    }

    for (int kt = 0; kt <= qt; ++kt) {
        const int k0 = kt * KT_;
        __syncthreads();
        *(uint4*)&Ks[skey][sdc * 8] = rk0.u;
        *(uint4*)&Ks[skey + 16][sdc * 8] = rk1.u;
#pragma unroll
        for (int j = 0; j < 8; ++j) {
            const int d = sdc * 8 + j;
            const int f = ((j >> 1) & 3) ^ (sdc & 3);
            const int grp = (skey >> 2) ^ f;
            Vt[d * 16 + grp * 4 + (skey & 3)] = (unsigned)rv0.s[j] | ((unsigned)rv1.s[j] << 16);
        }
        __syncthreads();
        if (kt < qt) {
            const size_t o0 = (size_t)(k0 + KT_ + skey) * ldkv + sdc * 8;
            const size_t o1 = o0 + (size_t)16 * ldkv;
            rk0.u = *(const uint4*)(Kg + o0);
            rk1.u = *(const uint4*)(Kg + o1);
            rv0.u = *(const uint4*)(Vg + o0);
            rv1.u = *(const uint4*)(Vg + o1);
        }

        f32x4 s0[2] = {}, s1[2] = {};
#pragma unroll
        for (int c = 0; c < 4; ++c) {
            bf16x8 kb0 = *(const bf16x8*)&Ks[r][c * 32 + quad * 8];
            bf16x8 kb1 = *(const bf16x8*)&Ks[16 + r][c * 32 + quad * 8];
#pragma unroll
            for (int t = 0; t < 2; ++t) {
                s0[t] = __builtin_amdgcn_mfma_f32_16x16x32_bf16(qf[t][c], kb0, s0[t], 0, 0, 0);
                s1[t] = __builtin_amdgcn_mfma_f32_16x16x32_bf16(qf[t][c], kb1, s1[t], 0, 0, 0);
            }
        }

        const bool bnd = (kt == qt);
#pragma unroll
        for (int t = 0; t < 2; ++t) {
            float mt[4];
#pragma unroll
            for (int g = 0; g < 4; ++g) {
                s0[t][g] *= SC2;
                s1[t][g] *= SC2;
                if (bnd) {
                    const int qrow = q0 + t * 16 + quad * 4 + g;
                    if (k0 + r > qrow)      s0[t][g] = -1e38f;
                    if (k0 + 16 + r > qrow) s1[t][g] = -1e38f;
                }
                mt[g] = fmaxf(s0[t][g], s1[t][g]);
            }
#pragma unroll
            for (int msk = 1; msk < 16; msk <<= 1) {
#pragma unroll
                for (int g = 0; g < 4; ++g) mt[g] = fmaxf(mt[g], __shfl_xor(mt[g], msk, 64));
            }
            bool upd = false;
#pragma unroll
            for (int g = 0; g < 4; ++g) upd |= (mt[g] > m_i[t][g]);
            if (__ballot(upd)) {
#pragma unroll
                for (int g = 0; g < 4; ++g) {
                    const float mn = fmaxf(m_i[t][g], mt[g]);
                    const float al = exp2f(m_i[t][g] - mn);
                    m_i[t][g] = mn;
                    lacc[t][g] *= al;
#pragma unroll
                    for (int ns = 0; ns < 8; ++ns) oacc[t][ns][g] *= al;
                }
            }
#pragma unroll
            for (int g = 0; g < 4; ++g) {
                const float p0 = exp2f(s0[t][g] - m_i[t][g]);
                const float p1 = exp2f(s1[t][g] - m_i[t][g]);
                const int row = quad * 4 + g;
                Pb[w][t][row][(((r >> 2) ^ quad) & 3) * 4 + (r & 3)] = packbf2(p0, p1);
            }
        }

        const int pgrp = ((quad ^ (r >> 2)) & 3) * 4;
        bf16x8 pf0 = *(const bf16x8*)&Pb[w][0][r][pgrp];
        bf16x8 pf1 = *(const bf16x8*)&Pb[w][1][r][pgrp];

        lacc[0] = __builtin_amdgcn_mfma_f32_16x16x32_bf16(pf0, ones, lacc[0], 0, 0, 0);
        lacc[1] = __builtin_amdgcn_mfma_f32_16x16x32_bf16(pf1, ones, lacc[1], 0, 0, 0);

#pragma unroll
        for (int ns = 0; ns < 8; ++ns) {
            const int d = ns * 16 + r;
            const int f = ((r >> 1) & 3) ^ ((2 * ns + (r >> 3)) & 3);
            bf16x8 vf = *(const bf16x8*)&Vt[d * 16 + ((quad ^ f) & 3) * 4];
            oacc[0][ns] = __builtin_amdgcn_mfma_f32_16x16x32_bf16(pf0, vf, oacc[0][ns], 0, 0, 0);
            oacc[1][ns] = __builtin_amdgcn_mfma_f32_16x16x32_bf16(pf1, vf, oacc[1][ns], 0, 0, 0);
        }
    }

#pragma unroll
    for (int t = 0; t < 2; ++t) {
#pragma unroll
        for (int g = 0; g < 4; ++g) {
            const float inv = 1.0f / lacc[t][g];
            const int qrow = q0 + t * 16 + quad * 4 + g;
            __hip_bfloat16* op = O + (size_t)(b * S_ + qrow) * ldo + h * D_;
#pragma unroll
            for (int ns = 0; ns < 8; ++ns)
                op[ns * 16 + r] = __float2bfloat16(oacc[t][ns][g] * inv);
        }
    }
}

// ---------------------------------------------------------------------------
extern "C" void kernel_launch(void* const* d_in, const int* in_sizes, int n_in,
                              void* d_out, int out_size, void* d_ws, size_t ws_size,
                              hipStream_t stream) {
    const void* x    = d_in[0];
    const void* cosp = d_in[1];
    const void* sinp = d_in[2];
    const void* Wq   = d_in[3];
    const void* Wk   = d_in[4];
    const void* Wv   = d_in[5];
    const void* Wo   = d_in[6];

    const int M = B_ * S_;                 // 4096
    const size_t MB = 1ull << 20;

    if (ws_size >= 28 * MB + 64) {
        // Fast path. ws: [0,16M)=xb then ao; [16M,28M)=Wqkv, then Wo at [16M,24M)
        // and packed-V at [24M,28M); flag at 28M.
        // d_out: qkv bf16 [4096,3072] (24 MB), packed-K at [24M,28M), then output.
        char* ws = (char*)d_ws;
        bf16_t* xb = (bf16_t*)ws;
        bf16_t* wb = (bf16_t*)(ws + 16 * MB);
        bf16_t* wo = (bf16_t*)(ws + 16 * MB);
        unsigned* vp4 = (unsigned*)(ws + 24 * MB);
        bf16_t* ao = (bf16_t*)ws;
        int* flag  = (int*)(ws + 28 * MB);
        bf16_t* qkv = (bf16_t*)d_out;
        bf16_t* kp8 = (bf16_t*)((char*)d_out + 24 * MB);

        detect_dtype<<<1, 64, 0, stream>>>((const unsigned*)x, flag);

        // convert x, Wq, Wk, Wv -> bf16 (Wqkv contiguous [3072, 2048])
        Cseg sx{x,  xb,                          (B_ * S_ * HID_) / 8};
        Cseg sq{Wq, wb,                          (H_ * D_ * HID_) / 8};
        Cseg sk{Wk, wb + (size_t)2048 * HID_,    (HKV_ * D_ * HID_) / 8};
        Cseg sv{Wv, wb + (size_t)2560 * HID_,    (HKV_ * D_ * HID_) / 8};
        convert_bf16<<<dim3(4096, 4), 256, 0, stream>>>(sx, sq, sk, sv, flag);

        // Fused QKV projection: [4096,2048] x [3072,2048]^T -> qkv [4096,3072]
        gemm_lds<<<dim3(3072 / 128, M / 128), 256, 0, stream>>>(xb, wb, qkv, M, 3072, HID_, flag, 0);

        // convert Wo -> bf16 (wb dead; wo overlays wb)
        Cseg so{Wo, wo, (HID_ * H_ * D_) / 8};
        convert_bf16<<<dim3(2048, 1), 256, 0, stream>>>(so, so, so, so, flag);

        // pack V (no RoPE on V): qkv cols [2560,3072) -> vp4
        v_pack<<<(B_ * HKV_ * D_ * 64 * 16) / 256, 256, 0, stream>>>(
            (const __hip_bfloat16*)(qkv + 2560), vp4, 3072);

        // RoPE + RMSNorm in-place: q cols [0,2048), k cols [2048,2560)
        rope_rms<<<(B_ * S_ * H_) / 4, 256, 0, stream>>>((__hip_bfloat16*)qkv, cosp, sinp, H_, 3072, flag);
        rope_rms<<<(B_ * S_ * HKV_) / 4, 256, 0, stream>>>((__hip_bfloat16*)(qkv + 2048), cosp, sinp, HKV_, 3072, flag);

        // pack post-RoPE K into swizzled per-tile layout
        k_pack<<<dim3(1024), 256, 0, stream>>>((const __hip_bfloat16*)(qkv + 2048), kp8);

        // Flash attention v9: Q strided in qkv, K/V packed; O -> ao (xb dead)
        attn_flash9<<<dim3(256), 512, 0, stream>>>(
            (const __hip_bfloat16*)qkv, kp8, vp4, (__hip_bfloat16*)ao);

        // Output projection: ao x Wo^T -> d_out (fp32 if flag=0)
        gemm_lds<<<dim3(HID_ / 128, M / 128), 256, 0, stream>>>(ao, wo, d_out, M, HID_, H_ * D_, flag, 1);
    } else {
        // Fallback: proven path (ws >= 16 MB + 4).
        __hip_bfloat16* qb = (__hip_bfloat16*)d_ws;
        int* flag = (int*)((char*)d_ws + (size_t)M * (H_ * D_) * sizeof(__hip_bfloat16));
        __hip_bfloat16* kb = (__hip_bfloat16*)d_out;
        __hip_bfloat16* vb = kb + (size_t)M * (HKV_ * D_);

        detect_dtype<<<1, 64, 0, stream>>>((const unsigned*)x, flag);

        gemm_bt<<<dim3((H_ * D_) / 64, M / 64), 256, 0, stream>>>(x, Wq, qb, M, H_ * D_, HID_, flag, 0);
        gemm_bt<<<dim3((HKV_ * D_) / 64, M / 64), 256, 0, stream>>>(x, Wk, kb, M, HKV_ * D_, HID_, flag, 0);
        gemm_bt<<<dim3((HKV_ * D_) / 64, M / 64), 256, 0, stream>>>(x, Wv, vb, M, HKV_ * D_, HID_, flag, 0);

        rope_rms<<<(B_ * S_ * H_) / 4, 256, 0, stream>>>(qb, cosp, sinp, H_, H_ * D_, flag);
        rope_rms<<<(B_ * S_ * HKV_) / 4, 256, 0, stream>>>(kb, cosp, sinp, HKV_, HKV_ * D_, flag);

        attn_flash3<<<dim3(S_ / 32, B_ * HKV_), 256, 0, stream>>>(qb, kb, vb, qb, H_ * D_, HKV_ * D_, H_ * D_);

        gemm_bt<<<dim3(HID_ / 64, M / 64), 256, 0, stream>>>(qb, Wo, d_out, M, HID_, H_ * D_, flag, 1);
    }
}